// Round 2
// baseline (4454.831 us; speedup 1.0000x reference)
//
#include <hip/hip_runtime.h>
#include <hip/hip_bf16.h>
#include <math.h>

#define SEQ    2048
#define BATCH  8
#define DMODEL 512
#define NHEADS 8
#define DK     64
#define DFF    2048
#define MROWS  (SEQ * BATCH)   // 16384

typedef __hip_bfloat16 bf16;
typedef unsigned int   u32;
typedef unsigned short u16;

__device__ __forceinline__ float b2f(bf16 v) { return __bfloat162float(v); }
__device__ __forceinline__ u16 f2u(float f) { bf16 h = __float2bfloat16(f); return *(u16*)&h; }
__device__ __forceinline__ void unpack2(u32 u, float& a, float& b) {
    a = __uint_as_float(u << 16);
    b = __uint_as_float(u & 0xFFFF0000u);
}
__device__ __forceinline__ u32 pack2(float a, float b) {
    return ((u32)f2u(b) << 16) | (u32)f2u(a);
}
// external-tensor load: dtype decided at runtime by probe flag (0=bf16, 1=fp32)
__device__ __forceinline__ float ldE(const void* p, long off, int f32) {
    return f32 ? ((const float*)p)[off] : b2f(((const bf16*)p)[off]);
}

// ---------------------------------------------------------------------------
// Dtype probe: read first 2048 u16 of x as bf16. True bf16 N(0,1): ~100% of
// values in (2^-30, 2^30). fp32 misread as bf16: low-mantissa halves are
// uniform 16-bit garbage -> only ~62% in range. flag=1 means fp32 inputs.
// ---------------------------------------------------------------------------
__global__ __launch_bounds__(256) void probe_kernel(const void* __restrict__ x,
                                                    int* __restrict__ flag)
{
    int tid = threadIdx.x;
    const u16* u = (const u16*)x;
    int cnt = 0;
    #pragma unroll
    for (int i = 0; i < 8; i++) {
        u16 e = u[tid * 8 + i];
        float v = __uint_as_float(((u32)e) << 16);
        float a = fabsf(v);
        if (a > 9.313226e-10f && a < 1.0737418e9f) cnt++;   // (2^-30, 2^30); NaN/Inf fail
    }
    __shared__ int sh[256];
    sh[tid] = cnt;
    __syncthreads();
    for (int s = 128; s > 0; s >>= 1) {
        if (tid < s) sh[tid] += sh[tid + s];
        __syncthreads();
    }
    if (tid == 0) *flag = (sh[0] < 1700) ? 1 : 0;
}

// ---------------------------------------------------------------------------
// Tiled GEMM: C[m,n] = sum_k A[m,k]*B[.] + bias[n]; C stored bf16.
// A_EXT: A is an external tensor (dtype per flag, generalized row addressing
//        off(m) = (m%a_sp)*a_inner + (m/a_sp)*a_outer to absorb (S,B,D) views)
// !A_EXT: A is internal bf16 plain row-major.
// B (weights) and bias always external. Tile 64x64, BK=16, 256 thr, 4x4/thr.
// ---------------------------------------------------------------------------
template<bool A_EXT, bool B_TRANS, bool RELU>
__global__ __launch_bounds__(256) void gemm_kernel(
    const void* __restrict__ Av, const void* __restrict__ Bw,
    const void* __restrict__ bias, bf16* __restrict__ C,
    int M, int N, int K, int a_sp, long a_inner, long a_outer,
    const int* __restrict__ flagp)
{
    const int f32 = *flagp;
    __shared__ float As[16][65];
    __shared__ float Bs[16][64];
    int tid = threadIdx.x;
    int tx = tid & 15, ty = tid >> 4;
    int m0 = blockIdx.x * 64, n0 = blockIdx.y * 64;
    float acc[4][4] = {};

    for (int k0 = 0; k0 < K; k0 += 16) {
        #pragma unroll
        for (int i = 0; i < 4; i++) {
            int l = tid + i * 256;          // 0..1023
            int kk = l & 15, r = l >> 4;
            int m = m0 + r;
            long off = (long)(m % a_sp) * a_inner + (long)(m / a_sp) * a_outer
                       + (long)(k0 + kk);
            As[kk][r] = A_EXT ? ldE(Av, off, f32) : b2f(((const bf16*)Av)[off]);
        }
        #pragma unroll
        for (int i = 0; i < 4; i++) {
            int l = tid + i * 256;
            int kk, n; long off;
            if (B_TRANS) { kk = l & 15; n = l >> 4; off = (long)(n0 + n) * K + (k0 + kk); }
            else         { n = l & 63; kk = l >> 6; off = (long)(k0 + kk) * N + (n0 + n); }
            Bs[kk][n] = ldE(Bw, off, f32);
        }
        __syncthreads();
        #pragma unroll
        for (int kk = 0; kk < 16; kk++) {
            float4 bv4 = *(const float4*)&Bs[kk][tx * 4];
            float b4[4] = {bv4.x, bv4.y, bv4.z, bv4.w};
            float a4[4];
            #pragma unroll
            for (int i = 0; i < 4; i++) a4[i] = As[kk][ty * 4 + i];
            #pragma unroll
            for (int i = 0; i < 4; i++)
                #pragma unroll
                for (int j = 0; j < 4; j++)
                    acc[i][j] = fmaf(a4[i], b4[j], acc[i][j]);
        }
        __syncthreads();
    }

    #pragma unroll
    for (int i = 0; i < 4; i++) {
        int m = m0 + ty * 4 + i;
        float vb[4];
        #pragma unroll
        for (int j = 0; j < 4; j++) {
            float v = acc[i][j] + ldE(bias, n0 + tx * 4 + j, f32);
            if (RELU) v = fmaxf(v, 0.0f);
            vb[j] = v;
        }
        uint2 o2 = { pack2(vb[0], vb[1]), pack2(vb[2], vb[3]) };
        *(uint2*)&C[(long)m * N + (n0 + tx * 4)] = o2;
    }
}

// ---------------------------------------------------------------------------
// Recurrence: h_t = tanh(h_{t-1}*w_diag + r_t), w_diag[o] = sum_k Wh[o*64+k]
// RH internal bf16 (B,S,D) plain, updated in place. h carried in fp32.
// ---------------------------------------------------------------------------
__global__ __launch_bounds__(256) void recur_kernel(bf16* __restrict__ RH,
                                                    const void* __restrict__ Wh,
                                                    const int* __restrict__ flagp)
{
    const int f32 = *flagp;
    int idx = blockIdx.x * 256 + threadIdx.x;   // 0 .. B*DMODEL-1
    int b = idx >> 9, o = idx & 511;
    float w = 0.0f;
    #pragma unroll
    for (int k = 0; k < DK; k++) w += ldE(Wh, (long)o * DK + k, f32);
    bf16* base = RH + (long)b * SEQ * DMODEL + o;
    float h = 0.0f;
    for (int s = 0; s < SEQ; s++) {
        float r = b2f(base[(long)s * DMODEL]);
        h = tanhf(fmaf(h, w, r));
        base[(long)s * DMODEL] = __float2bfloat16(h);
    }
}

// ---------------------------------------------------------------------------
// Attention, flash-style online softmax. Mask ADDS +1.0 for k > q (torch
// triu-bool quirk) -- softmax over ALL keys. 1 thread = 1 q row.
// Q,H,V,O internal bf16 (B,S,D) plain, head slice at col hd*DK.
// ---------------------------------------------------------------------------
__global__ __launch_bounds__(256) void attn_kernel(const bf16* __restrict__ Q,
                                                   const bf16* __restrict__ Hb,
                                                   const bf16* __restrict__ Vb,
                                                   bf16* __restrict__ O)
{
    __shared__ float Ht[64][64];
    __shared__ float Vt[64][64];
    int tid = threadIdx.x;
    int qrow = blockIdx.x * 256 + tid;            // 0..SEQ-1
    int bh = blockIdx.y;
    int b = bh / NHEADS, hd = bh % NHEADS;
    const float scale = 0.125f;                   // 1/sqrt(64)

    const u32* qp = (const u32*)(Q + ((long)(b * SEQ + qrow)) * DMODEL + hd * DK);
    float q[64], o[64];
    #pragma unroll
    for (int i = 0; i < 32; i++) unpack2(qp[i], q[2 * i], q[2 * i + 1]);
    #pragma unroll
    for (int i = 0; i < 64; i++) o[i] = 0.0f;
    float mx = -1e30f, l = 0.0f;

    for (int kt = 0; kt < SEQ; kt += 64) {
        #pragma unroll
        for (int i = 0; i < 2; i++) {
            int idx = tid + i * 256;              // 0..511, 8-elem group
            int r = idx >> 3, c8 = (idx & 7) * 8;
            long goff = ((long)(b * SEQ + kt + r)) * DMODEL + hd * DK + c8;
            uint4 th = *(const uint4*)(Hb + goff);
            unpack2(th.x, Ht[r][c8 + 0], Ht[r][c8 + 1]);
            unpack2(th.y, Ht[r][c8 + 2], Ht[r][c8 + 3]);
            unpack2(th.z, Ht[r][c8 + 4], Ht[r][c8 + 5]);
            unpack2(th.w, Ht[r][c8 + 6], Ht[r][c8 + 7]);
            uint4 tv = *(const uint4*)(Vb + goff);
            unpack2(tv.x, Vt[r][c8 + 0], Vt[r][c8 + 1]);
            unpack2(tv.y, Vt[r][c8 + 2], Vt[r][c8 + 3]);
            unpack2(tv.z, Vt[r][c8 + 4], Vt[r][c8 + 5]);
            unpack2(tv.w, Vt[r][c8 + 6], Vt[r][c8 + 7]);
        }
        __syncthreads();
        for (int kk = 0; kk < 64; kk++) {
            float d0 = 0, d1 = 0, d2 = 0, d3 = 0;
            #pragma unroll
            for (int i = 0; i < 64; i += 16) {
                float4 h0 = *(const float4*)&Ht[kk][i];
                float4 h1 = *(const float4*)&Ht[kk][i + 4];
                float4 h2 = *(const float4*)&Ht[kk][i + 8];
                float4 h3 = *(const float4*)&Ht[kk][i + 12];
                d0 = fmaf(q[i+0], h0.x, d0); d0 = fmaf(q[i+1], h0.y, d0);
                d0 = fmaf(q[i+2], h0.z, d0); d0 = fmaf(q[i+3], h0.w, d0);
                d1 = fmaf(q[i+4], h1.x, d1); d1 = fmaf(q[i+5], h1.y, d1);
                d1 = fmaf(q[i+6], h1.z, d1); d1 = fmaf(q[i+7], h1.w, d1);
                d2 = fmaf(q[i+8], h2.x, d2); d2 = fmaf(q[i+9], h2.y, d2);
                d2 = fmaf(q[i+10], h2.z, d2); d2 = fmaf(q[i+11], h2.w, d2);
                d3 = fmaf(q[i+12], h3.x, d3); d3 = fmaf(q[i+13], h3.y, d3);
                d3 = fmaf(q[i+14], h3.z, d3); d3 = fmaf(q[i+15], h3.w, d3);
            }
            int kglob = kt + kk;
            float s = (d0 + d1 + d2 + d3) * scale + ((kglob > qrow) ? 1.0f : 0.0f);
            float mn = fmaxf(mx, s);
            if (mn > mx) {
                float alpha = __expf(mx - mn);
                l *= alpha;
                #pragma unroll
                for (int i = 0; i < 64; i++) o[i] *= alpha;
                mx = mn;
            }
            float p = __expf(s - mx);
            l += p;
            #pragma unroll
            for (int i = 0; i < 64; i += 4) {
                float4 vv = *(const float4*)&Vt[kk][i];
                o[i]   = fmaf(p, vv.x, o[i]);
                o[i+1] = fmaf(p, vv.y, o[i+1]);
                o[i+2] = fmaf(p, vv.z, o[i+2]);
                o[i+3] = fmaf(p, vv.w, o[i+3]);
            }
        }
        __syncthreads();
    }
    float inv = 1.0f / l;
    u32* op = (u32*)(O + ((long)(b * SEQ + qrow)) * DMODEL + hd * DK);
    #pragma unroll
    for (int i = 0; i < 32; i++) op[i] = pack2(o[2*i] * inv, o[2*i+1] * inv);
}

// ---------------------------------------------------------------------------
// Residual + LayerNorm over 512. One block per row m = b*SEQ + s.
// FIRST: a = x external (S,B,D), rsd = AO bf16 plain -> X1 bf16 plain
// !FIRST: a = X1 bf16 plain, rsd = FF2 bf16 plain -> d_out external (S,B,D)
// ---------------------------------------------------------------------------
template<bool FIRST>
__global__ __launch_bounds__(256) void ln_kernel(const void* __restrict__ a,
                                                 const bf16* __restrict__ rsd,
                                                 const void* __restrict__ g,
                                                 const void* __restrict__ beta,
                                                 void* __restrict__ outp,
                                                 const int* __restrict__ flagp)
{
    const int f32 = *flagp;
    int m = blockIdx.x;
    int bb = m / SEQ, s = m % SEQ;
    long plain = (long)m * DMODEL;
    long funny = ((long)s * BATCH + bb) * DMODEL;
    int tid = threadIdx.x;

    float v[2];
    #pragma unroll
    for (int i = 0; i < 2; i++) {
        int d = tid + i * 256;
        float av = FIRST ? ldE(a, funny + d, f32)
                         : b2f(((const bf16*)a)[plain + d]);
        v[i] = av + b2f(rsd[plain + d]);
    }
    float s1 = v[0] + v[1];
    float s2 = v[0] * v[0] + v[1] * v[1];
    #pragma unroll
    for (int off = 32; off > 0; off >>= 1) {
        s1 += __shfl_down(s1, off);
        s2 += __shfl_down(s2, off);
    }
    __shared__ float w1[4], w2[4];
    int wid = tid >> 6, lane = tid & 63;
    if (lane == 0) { w1[wid] = s1; w2[wid] = s2; }
    __syncthreads();
    float t1 = w1[0] + w1[1] + w1[2] + w1[3];
    float t2 = w2[0] + w2[1] + w2[2] + w2[3];
    float mu = t1 * (1.0f / DMODEL);
    float var = t2 * (1.0f / DMODEL) - mu * mu;
    float rs = rsqrtf(var + 1e-5f);
    #pragma unroll
    for (int i = 0; i < 2; i++) {
        int d = tid + i * 256;
        float r = (v[i] - mu) * rs * ldE(g, d, f32) + ldE(beta, d, f32);
        if (FIRST) {
            ((bf16*)outp)[plain + d] = __float2bfloat16(r);
        } else {
            if (f32) ((float*)outp)[funny + d] = r;
            else     ((bf16*)outp)[funny + d] = __float2bfloat16(r);
        }
    }
}

// ---------------------------------------------------------------------------
extern "C" void kernel_launch(void* const* d_in, const int* in_sizes, int n_in,
                              void* d_out, int out_size, void* d_ws, size_t ws_size,
                              hipStream_t stream)
{
    (void)in_sizes; (void)n_in; (void)out_size; (void)ws_size;
    const void* x   = d_in[0];
    const void* Wq  = d_in[1];
    const void* bq  = d_in[2];
    const void* Wv  = d_in[3];
    const void* bv  = d_in[4];
    const void* Wr  = d_in[5];
    const void* br  = d_in[6];
    const void* Wh  = d_in[7];
    const void* Wo  = d_in[8];
    const void* bo  = d_in[9];
    const void* g1  = d_in[10];
    const void* b1  = d_in[11];
    const void* Wf1 = d_in[12];
    const void* bf1 = d_in[13];
    const void* Wf2 = d_in[14];
    const void* bf2 = d_in[15];
    const void* g2  = d_in[16];
    const void* b2  = d_in[17];

    // workspace: internal bf16 intermediates, peak 96 MiB (+4B flag)
    bf16* W   = (bf16*)d_ws;
    bf16* Q   = W;                 // [0, 8M) elems
    bf16* V   = W + (1u << 23);    // [8M, 16M)
    bf16* RH  = W + (2u << 23);    // [16M, 24M)  R -> H in place
    bf16* O   = W + (3u << 23);    // [24M, 32M)
    bf16* AO  = Q;                 // reuse (Q dead after attention)
    bf16* X1  = V;                 // reuse (V dead after attention)
    bf16* FFH = RH;                // [16M, 48M) over RH+O (dead after Wo)
    bf16* FF2 = Q;                 // reuse (AO dead after LN1)
    int* flag = (int*)((char*)d_ws + (size_t)96 * 1024 * 1024);

    dim3 blk(256);
    probe_kernel<<<1, blk, 0, stream>>>(x, flag);

    // Q/V/R projections: A = x external (S,B,D) view, B = W (N x K), +bias
    dim3 gp(MROWS / 64, DMODEL / 64);
    gemm_kernel<true, true, false><<<gp, blk, 0, stream>>>(
        x, Wq, bq, Q, MROWS, DMODEL, DMODEL, SEQ, (long)BATCH * DMODEL, (long)DMODEL, flag);
    gemm_kernel<true, true, false><<<gp, blk, 0, stream>>>(
        x, Wv, bv, V, MROWS, DMODEL, DMODEL, SEQ, (long)BATCH * DMODEL, (long)DMODEL, flag);
    gemm_kernel<true, true, false><<<gp, blk, 0, stream>>>(
        x, Wr, br, RH, MROWS, DMODEL, DMODEL, SEQ, (long)BATCH * DMODEL, (long)DMODEL, flag);

    // recurrence R -> H (in place)
    recur_kernel<<<(BATCH * DMODEL) / 256, blk, 0, stream>>>(RH, Wh, flag);

    // attention (full softmax with +1 pseudo-mask)
    attn_kernel<<<dim3(SEQ / 256, BATCH * NHEADS), blk, 0, stream>>>(Q, RH, V, O);

    // Wo projection: A = O internal, B = Wo (N x K), +bo
    gemm_kernel<false, true, false><<<gp, blk, 0, stream>>>(
        O, Wo, bo, AO, MROWS, DMODEL, DMODEL, MROWS, (long)DMODEL, 0L, flag);

    // LN1: x + AO -> X1
    ln_kernel<true><<<MROWS, blk, 0, stream>>>(x, AO, g1, b1, X1, flag);

    // FF1: A = X1 internal, B = Wf1 (K x N), +bf1, relu
    gemm_kernel<false, false, true><<<dim3(MROWS / 64, DFF / 64), blk, 0, stream>>>(
        X1, Wf1, bf1, FFH, MROWS, DFF, DMODEL, MROWS, (long)DMODEL, 0L, flag);

    // FF2: A = FFH internal, B = Wf2 (K x N), +bf2
    gemm_kernel<false, false, false><<<gp, blk, 0, stream>>>(
        FFH, Wf2, bf2, FF2, MROWS, DMODEL, DFF, MROWS, (long)DFF, 0L, flag);

    // LN2: X1 + FF2 -> d_out (external dtype, (S,B,D))
    ln_kernel<false><<<MROWS, blk, 0, stream>>>(X1, FF2, g2, b2, d_out, flag);
}

// Round 3
// 1151.320 us; speedup vs baseline: 3.8693x; 3.8693x over previous
//
#include <hip/hip_runtime.h>
#include <hip/hip_bf16.h>
#include <math.h>

#define SEQ    2048
#define BATCH  8
#define DMODEL 512
#define NHEADS 8
#define DK     64
#define DFF    2048
#define MROWS  16384

typedef __hip_bfloat16 bf16;
typedef unsigned int   u32;
typedef unsigned short u16;
typedef __attribute__((ext_vector_type(8))) short short8;   // 8 bf16 = 4 VGPR
typedef __attribute__((ext_vector_type(4))) float f32x4;

__device__ __forceinline__ float b2f(bf16 v) { return __bfloat162float(v); }
__device__ __forceinline__ bf16  f2b(float f) { return __float2bfloat16(f); }
__device__ __forceinline__ u16 f2u(float f) { bf16 h = __float2bfloat16(f); return *(u16*)&h; }
__device__ __forceinline__ u32 pack2(float a, float b) {
    return ((u32)f2u(b) << 16) | (u32)f2u(a);
}
// external-tensor load: dtype decided at runtime by probe flag (0=bf16, 1=fp32)
__device__ __forceinline__ float ldE(const void* p, long off, int f32) {
    return f32 ? ((const float*)p)[off] : b2f(((const bf16*)p)[off]);
}
// async global->LDS, 16B per lane; lds base must be wave-uniform
__device__ __forceinline__ void async16(bf16* lds, const bf16* g) {
    __builtin_amdgcn_global_load_lds(
        (const __attribute__((address_space(1))) void*)g,
        (__attribute__((address_space(3))) void*)lds, 16, 0, 0);
}

// ---------------------------------------------------------------------------
// Dtype probe (worked in round 2): flag=1 means fp32 inputs.
// ---------------------------------------------------------------------------
__global__ __launch_bounds__(256) void probe_kernel(const void* __restrict__ x,
                                                    int* __restrict__ flag)
{
    int tid = threadIdx.x;
    const u16* u = (const u16*)x;
    int cnt = 0;
    #pragma unroll
    for (int i = 0; i < 8; i++) {
        u16 e = u[tid * 8 + i];
        float v = __uint_as_float(((u32)e) << 16);
        float a = fabsf(v);
        if (a > 9.313226e-10f && a < 1.0737418e9f) cnt++;
    }
    __shared__ int sh[256];
    sh[tid] = cnt;
    __syncthreads();
    for (int s = 128; s > 0; s >>= 1) {
        if (tid < s) sh[tid] += sh[tid + s];
        __syncthreads();
    }
    if (tid == 0) *flag = (sh[0] < 1700) ? 1 : 0;
}

// ---------------------------------------------------------------------------
// x (S,B,D) external dtype -> xb bf16 plain [b*SEQ+s][512]
// ---------------------------------------------------------------------------
__global__ __launch_bounds__(256) void convert_x(const void* __restrict__ x,
                                                 bf16* __restrict__ xb,
                                                 const int* __restrict__ flagp)
{
    const int f32 = *flagp;
    int gid = blockIdx.x * 256 + threadIdx.x;      // 0..1048575
    int row_in = gid >> 6;                         // s*8+b
    int d8 = (gid & 63) * 8;
    int s = row_in >> 3, b = row_in & 7;
    long src = (long)row_in * 512 + d8;
    long dst = ((long)b * SEQ + s) * 512 + d8;
    if (f32) {
        const float* xf = (const float*)x;
        float4 a = *(const float4*)(xf + src);
        float4 c = *(const float4*)(xf + src + 4);
        u32 o[4] = { pack2(a.x,a.y), pack2(a.z,a.w), pack2(c.x,c.y), pack2(c.z,c.w) };
        *(uint4*)(xb + dst) = *(uint4*)o;
    } else {
        *(uint4*)(xb + dst) = *(const uint4*)((const bf16*)x + src);
    }
}

// ---------------------------------------------------------------------------
// Pack/convert all weights to bf16 [N][K] form.
//  Wqvr[1536][512] = {Wq;Wv;Wr}; Wob[512][512]; Wf1t[n][k]=Wf1[k][n];
//  Wf2t[n][k]=Wf2[k][n]; biases bqvr(1536), bob, bf1b, bf2b.
// ---------------------------------------------------------------------------
__global__ __launch_bounds__(256) void prep_weights(
    const void* Wq, const void* Wv, const void* Wr, const void* Wo,
    const void* Wf1, const void* Wf2,
    const void* bq, const void* bv, const void* br, const void* bo,
    const void* bf1, const void* bf2,
    bf16* __restrict__ Wqvr, bf16* __restrict__ Wob,
    bf16* __restrict__ Wf1t, bf16* __restrict__ Wf2t,
    bf16* __restrict__ bqvr, bf16* __restrict__ bob,
    bf16* __restrict__ bf1b, bf16* __restrict__ bf2b,
    const int* __restrict__ flagp)
{
    const int f32 = *flagp;
    long g = (long)blockIdx.x * 256 + threadIdx.x;   // < 3150336
    if (g < 786432) {
        const void* src = (g < 262144) ? Wq : (g < 524288) ? Wv : Wr;
        long j = g & 262143;
        Wqvr[g] = f2b(ldE(src, j, f32));
    } else if (g < 1048576) {
        long j = g - 786432;
        Wob[j] = f2b(ldE(Wo, j, f32));
    } else if (g < 2097152) {
        long j = g - 1048576;
        long n = j >> 9, k = j & 511;
        Wf1t[j] = f2b(ldE(Wf1, k * 2048 + n, f32));
    } else if (g < 3145728) {
        long j = g - 2097152;
        long n = j >> 11, k = j & 2047;
        Wf2t[j] = f2b(ldE(Wf2, k * 512 + n, f32));
    } else {
        long j = g - 3145728;
        if (j < 512)       bqvr[j]      = f2b(ldE(bq, j, f32));
        else if (j < 1024) bqvr[j]      = f2b(ldE(bv, j - 512, f32));
        else if (j < 1536) bqvr[j]      = f2b(ldE(br, j - 1024, f32));
        else if (j < 2048) bob[j-1536]  = f2b(ldE(bo, j - 1536, f32));
        else if (j < 4096) bf1b[j-2048] = f2b(ldE(bf1, j - 2048, f32));
        else if (j < 4608) bf2b[j-4096] = f2b(ldE(bf2, j - 4096, f32));
    }
}

// ---------------------------------------------------------------------------
// MFMA GEMM: C[m][n] = sum_k A[m][k]*W[n][k] + bias[n], all bf16, fp32 acc.
// 128x128 tile, BK=32, 256 thr = 4 waves (2x2), 4x4 16x16 tiles per wave.
// global_load_lds width-16 staging (m97 structure).
// A-frag: A[m=lane&15][k=quad*8+j]; B-frag: W[n=lane&15][k=quad*8+j];
// C/D: col=lane&15, row=quad*4+reg  [m89/m91 verified]
// ---------------------------------------------------------------------------
template<bool RELU>
__global__ __launch_bounds__(256) void mfma_gemm(
    const bf16* __restrict__ A, const bf16* __restrict__ W,
    const bf16* __restrict__ bias, bf16* __restrict__ C,
    int K, int lda, int ldc)
{
    __shared__ bf16 As[128 * 32];
    __shared__ bf16 Bs[128 * 32];
    const int tid = threadIdx.x;
    const int w = tid >> 6, lane = tid & 63;
    const int li = lane & 15, quad = lane >> 4;
    const int m0 = blockIdx.x * 128, n0 = blockIdx.y * 128;
    const int wm = (w >> 1) * 64, wn = (w & 1) * 64;
    const int srow = lane >> 2, scol = (lane & 3) * 8;

    f32x4 acc[4][4];
    const f32x4 z4 = {0.f, 0.f, 0.f, 0.f};
    #pragma unroll
    for (int i = 0; i < 4; i++)
        #pragma unroll
        for (int j = 0; j < 4; j++) acc[i][j] = z4;

    const bf16* ga = A + (long)(m0 + w * 32 + srow) * lda + scol;
    const bf16* gb = W + (long)(n0 + w * 32 + srow) * K + scol;
    bf16* lA0 = &As[(w * 32) * 32];
    bf16* lA1 = &As[(w * 32 + 16) * 32];
    bf16* lB0 = &Bs[(w * 32) * 32];
    bf16* lB1 = &Bs[(w * 32 + 16) * 32];

    for (int k0 = 0; k0 < K; k0 += 32) {
        __syncthreads();
        async16(lA0, ga);
        async16(lA1, ga + (long)16 * lda);
        async16(lB0, gb);
        async16(lB1, gb + (long)16 * K);
        ga += 32; gb += 32;
        __syncthreads();
        short8 af[4], bfr[4];
        #pragma unroll
        for (int t = 0; t < 4; t++)
            af[t] = *(const short8*)&As[(wm + t * 16 + li) * 32 + quad * 8];
        #pragma unroll
        for (int t = 0; t < 4; t++)
            bfr[t] = *(const short8*)&Bs[(wn + t * 16 + li) * 32 + quad * 8];
        #pragma unroll
        for (int i = 0; i < 4; i++)
            #pragma unroll
            for (int j = 0; j < 4; j++)
                acc[i][j] = __builtin_amdgcn_mfma_f32_16x16x32_bf16(
                    af[i], bfr[j], acc[i][j], 0, 0, 0);
    }

    #pragma unroll
    for (int i = 0; i < 4; i++) {
        #pragma unroll
        for (int j = 0; j < 4; j++) {
            int col = n0 + wn + j * 16 + li;
            float bb = b2f(bias[col]);
            #pragma unroll
            for (int r = 0; r < 4; r++) {
                int row = m0 + wm + i * 16 + quad * 4 + r;
                float v = acc[i][j][r] + bb;
                if (RELU) v = fmaxf(v, 0.f);
                C[(long)row * ldc + col] = f2b(v);
            }
        }
    }
}

// ---------------------------------------------------------------------------
// Recurrence on the R slice of QVR (cols 1024..1536, row stride 1536).
// ---------------------------------------------------------------------------
__global__ __launch_bounds__(256) void recur_kernel(bf16* __restrict__ QVR,
                                                    const void* __restrict__ Wh,
                                                    const int* __restrict__ flagp)
{
    const int f32 = *flagp;
    int idx = blockIdx.x * 256 + threadIdx.x;   // 0 .. 4095
    int b = idx >> 9, o = idx & 511;
    float w = 0.0f;
    #pragma unroll
    for (int k = 0; k < DK; k++) w += ldE(Wh, (long)o * DK + k, f32);
    bf16* base = QVR + (long)b * SEQ * 1536 + 1024 + o;
    float h = 0.0f;
    float r = b2f(base[0]);
    for (int s = 0; s < SEQ; s++) {
        float rn = (s + 1 < SEQ) ? b2f(base[(long)(s + 1) * 1536]) : 0.0f;
        h = tanhf(fmaf(h, w, r));
        base[(long)s * 1536] = f2b(h);
        r = rn;
    }
}

// ---------------------------------------------------------------------------
// MFMA flash attention. QVR bf16 [b*SEQ+s][1536]: Q=+0, V=+512, R/H=+1024.
// Mask ADDS +1.0 for key>q (torch triu-bool quirk): softmax over ALL keys.
// Block: 128 q-rows (4 waves x 32), K-tiles of 64 keys.
// QK^T: A=Q frag, B=K-tile rows [key][d]; softmax in C-layout (quad owns
// rows quad*4+r, 16-lane shfl_xor row reductions); P -> LDS -> A-frag;
// PV: B from V transposed in LDS [d][key]. O out bf16 [b*SEQ+s][512].
// ---------------------------------------------------------------------------
__global__ __launch_bounds__(256) void attn_mfma(const bf16* __restrict__ QVR,
                                                 bf16* __restrict__ O)
{
    __shared__ bf16 Kt[64 * 72];          // [key][d], pad 8
    __shared__ bf16 Vt[64 * 72];          // [d][key], pad 8
    __shared__ bf16 Pl[4 * 32 * 72];      // per-wave P [qrow][key], pad 8
    const int tid = threadIdx.x;
    const int w = tid >> 6, lane = tid & 63;
    const int li = lane & 15, quad = lane >> 4;
    const int b = blockIdx.y >> 3, hd = blockIdx.y & 7;
    const int q0 = blockIdx.x * 128;
    const long rowb = (long)b * SEQ;
    const bf16* Qb = QVR + hd * DK;
    const bf16* Hb = QVR + 1024 + hd * DK;
    const bf16* Vb = QVR + 512 + hd * DK;
    bf16* Pw = &Pl[w * 32 * 72];
    const f32x4 z4 = {0.f, 0.f, 0.f, 0.f};

    short8 qa[2][2];
    #pragma unroll
    for (int mt = 0; mt < 2; mt++)
        #pragma unroll
        for (int ks = 0; ks < 2; ks++)
            qa[mt][ks] = *(const short8*)&Qb[(rowb + q0 + w * 32 + mt * 16 + li) * 1536
                                             + ks * 32 + quad * 8];

    f32x4 oacc[2][4];
    float m_run[2][4], l_run[2][4];
    #pragma unroll
    for (int mt = 0; mt < 2; mt++) {
        #pragma unroll
        for (int dt = 0; dt < 4; dt++) oacc[mt][dt] = z4;
        #pragma unroll
        for (int r = 0; r < 4; r++) { m_run[mt][r] = -1e30f; l_run[mt][r] = 0.f; }
    }

    for (int kt = 0; kt < SEQ; kt += 64) {
        __syncthreads();
        #pragma unroll
        for (int i = 0; i < 2; i++) {
            int r = (tid >> 3) + i * 32;
            int c8 = (tid & 7) * 8;
            long goff = (rowb + kt + r) * 1536 + c8;
            uint4 hv = *(const uint4*)&Hb[goff];
            *(uint4*)&Kt[r * 72 + c8] = hv;
            uint4 vv = *(const uint4*)&Vb[goff];
            bf16 tmp[8];
            *(uint4*)tmp = vv;
            #pragma unroll
            for (int j = 0; j < 8; j++) Vt[(c8 + j) * 72 + r] = tmp[j];
        }
        __syncthreads();

        // ---- S = Q K^T ----
        f32x4 sa[2][4];
        #pragma unroll
        for (int mt = 0; mt < 2; mt++)
            #pragma unroll
            for (int nt = 0; nt < 4; nt++) sa[mt][nt] = z4;
        #pragma unroll
        for (int ks = 0; ks < 2; ks++) {
            short8 kb[4];
            #pragma unroll
            for (int nt = 0; nt < 4; nt++)
                kb[nt] = *(const short8*)&Kt[(nt * 16 + li) * 72 + ks * 32 + quad * 8];
            #pragma unroll
            for (int mt = 0; mt < 2; mt++)
                #pragma unroll
                for (int nt = 0; nt < 4; nt++)
                    sa[mt][nt] = __builtin_amdgcn_mfma_f32_16x16x32_bf16(
                        qa[mt][ks], kb[nt], sa[mt][nt], 0, 0, 0);
        }

        // ---- online softmax (rows quad*4+r, reduce across 16-lane group) ----
        #pragma unroll
        for (int mt = 0; mt < 2; mt++) {
            #pragma unroll
            for (int r = 0; r < 4; r++) {
                int qrow = q0 + w * 32 + mt * 16 + quad * 4 + r;
                float mval = -1e30f;
                #pragma unroll
                for (int nt = 0; nt < 4; nt++) {
                    int key = kt + nt * 16 + li;
                    float s = sa[mt][nt][r] * 0.125f + ((key > qrow) ? 1.0f : 0.0f);
                    sa[mt][nt][r] = s;
                    mval = fmaxf(mval, s);
                }
                #pragma unroll
                for (int d = 1; d < 16; d <<= 1) mval = fmaxf(mval, __shfl_xor(mval, d));
                float mnew = fmaxf(m_run[mt][r], mval);
                float alpha = __expf(m_run[mt][r] - mnew);
                m_run[mt][r] = mnew;
                float rs = 0.f;
                #pragma unroll
                for (int nt = 0; nt < 4; nt++) {
                    float p = __expf(sa[mt][nt][r] - mnew);
                    rs += p;
                    Pw[(mt * 16 + quad * 4 + r) * 72 + nt * 16 + li] = f2b(p);
                }
                #pragma unroll
                for (int d = 1; d < 16; d <<= 1) rs += __shfl_xor(rs, d);
                l_run[mt][r] = l_run[mt][r] * alpha + rs;
                #pragma unroll
                for (int dt = 0; dt < 4; dt++) oacc[mt][dt][r] *= alpha;
            }
        }

        // ---- O += P V ----
        #pragma unroll
        for (int ks = 0; ks < 2; ks++) {
            short8 vbf[4], pa[2];
            #pragma unroll
            for (int dt = 0; dt < 4; dt++)
                vbf[dt] = *(const short8*)&Vt[(dt * 16 + li) * 72 + ks * 32 + quad * 8];
            #pragma unroll
            for (int mt = 0; mt < 2; mt++)
                pa[mt] = *(const short8*)&Pw[(mt * 16 + li) * 72 + ks * 32 + quad * 8];
            #pragma unroll
            for (int mt = 0; mt < 2; mt++)
                #pragma unroll
                for (int dt = 0; dt < 4; dt++)
                    oacc[mt][dt] = __builtin_amdgcn_mfma_f32_16x16x32_bf16(
                        pa[mt], vbf[dt], oacc[mt][dt], 0, 0, 0);
        }
    }

    #pragma unroll
    for (int mt = 0; mt < 2; mt++)
        #pragma unroll
        for (int r = 0; r < 4; r++) {
            float inv = 1.0f / l_run[mt][r];
            long row = rowb + q0 + w * 32 + mt * 16 + quad * 4 + r;
            #pragma unroll
            for (int dt = 0; dt < 4; dt++)
                O[row * 512 + hd * 64 + dt * 16 + li] = f2b(oacc[mt][dt][r] * inv);
        }
}

// ---------------------------------------------------------------------------
// LN1: xb + AO (both bf16 plain) -> X1 bf16 plain
// ---------------------------------------------------------------------------
__global__ __launch_bounds__(256) void ln1_kernel(const bf16* __restrict__ xb,
                                                  const bf16* __restrict__ ao,
                                                  const void* __restrict__ g,
                                                  const void* __restrict__ beta,
                                                  bf16* __restrict__ x1,
                                                  const int* __restrict__ flagp)
{
    const int f32 = *flagp;
    long base = (long)blockIdx.x * 512;
    int tid = threadIdx.x;
    float v[2];
    #pragma unroll
    for (int i = 0; i < 2; i++) {
        int d = tid + i * 256;
        v[i] = b2f(xb[base + d]) + b2f(ao[base + d]);
    }
    float s1 = v[0] + v[1];
    float s2 = v[0] * v[0] + v[1] * v[1];
    #pragma unroll
    for (int off = 32; off > 0; off >>= 1) {
        s1 += __shfl_down(s1, off);
        s2 += __shfl_down(s2, off);
    }
    __shared__ float w1[4], w2[4];
    int wid = tid >> 6, lane = tid & 63;
    if (lane == 0) { w1[wid] = s1; w2[wid] = s2; }
    __syncthreads();
    float t1 = w1[0] + w1[1] + w1[2] + w1[3];
    float t2 = w2[0] + w2[1] + w2[2] + w2[3];
    float mu = t1 * (1.0f / DMODEL);
    float var = t2 * (1.0f / DMODEL) - mu * mu;
    float rs = rsqrtf(var + 1e-5f);
    #pragma unroll
    for (int i = 0; i < 2; i++) {
        int d = tid + i * 256;
        x1[base + d] = f2b((v[i] - mu) * rs * ldE(g, d, f32) + ldE(beta, d, f32));
    }
}

// ---------------------------------------------------------------------------
// LN2: X1 + FF2 -> d_out (external dtype, (S,B,D) layout)
// ---------------------------------------------------------------------------
__global__ __launch_bounds__(256) void ln2_kernel(const bf16* __restrict__ x1,
                                                  const bf16* __restrict__ ff2,
                                                  const void* __restrict__ g,
                                                  const void* __restrict__ beta,
                                                  void* __restrict__ outp,
                                                  const int* __restrict__ flagp)
{
    const int f32 = *flagp;
    int m = blockIdx.x;                 // b*SEQ + s
    int b = m >> 11, s = m & 2047;
    long plain = (long)m * 512;
    long funny = ((long)s * BATCH + b) * 512;
    int tid = threadIdx.x;
    float v[2];
    #pragma unroll
    for (int i = 0; i < 2; i++) {
        int d = tid + i * 256;
        v[i] = b2f(x1[plain + d]) + b2f(ff2[plain + d]);
    }
    float s1 = v[0] + v[1];
    float s2 = v[0] * v[0] + v[1] * v[1];
    #pragma unroll
    for (int off = 32; off > 0; off >>= 1) {
        s1 += __shfl_down(s1, off);
        s2 += __shfl_down(s2, off);
    }
    __shared__ float w1[4], w2[4];
    int wid = tid >> 6, lane = tid & 63;
    if (lane == 0) { w1[wid] = s1; w2[wid] = s2; }
    __syncthreads();
    float t1 = w1[0] + w1[1] + w1[2] + w1[3];
    float t2 = w2[0] + w2[1] + w2[2] + w2[3];
    float mu = t1 * (1.0f / DMODEL);
    float var = t2 * (1.0f / DMODEL) - mu * mu;
    float rs = rsqrtf(var + 1e-5f);
    #pragma unroll
    for (int i = 0; i < 2; i++) {
        int d = tid + i * 256;
        float r = (v[i] - mu) * rs * ldE(g, d, f32) + ldE(beta, d, f32);
        if (f32) ((float*)outp)[funny + d] = r;
        else     ((bf16*)outp)[funny + d] = f2b(r);
    }
}

// ---------------------------------------------------------------------------
extern "C" void kernel_launch(void* const* d_in, const int* in_sizes, int n_in,
                              void* d_out, int out_size, void* d_ws, size_t ws_size,
                              hipStream_t stream)
{
    (void)in_sizes; (void)n_in; (void)out_size; (void)ws_size;
    const void* x = d_in[0];

    // bf16 workspace layout (elements):
    bf16* W    = (bf16*)d_ws;
    bf16* xb   = W;                       // [0, 8M)   dead after LN1
    bf16* QVR  = W + (8u  << 20);         // [8M, 32M) Q|V|R cols, dead after attn
    bf16* Ob   = W + (32u << 20);         // [32M,40M) dead after Wo gemm
    bf16* AO   = W + (40u << 20);         // [40M,48M) dead after LN1
    bf16* X1   = W + (8u  << 20);         // reuse QVR head, alive until LN2
    bf16* FFH  = W + (16u << 20);         // [16M,48M) after LN1
    bf16* FF2  = W;                       // reuse xb
    int*  flag = (int*)((char*)d_ws + (size_t)96 * 1024 * 1024);
    bf16* Wt   = (bf16*)((char*)d_ws + (size_t)96 * 1024 * 1024 + 16);
    bf16* Wqvr = Wt;                      // [1536][512]
    bf16* Wob  = Wt + 786432;             // [512][512]
    bf16* Wf1t = Wt + 1048576;            // [2048][512]
    bf16* Wf2t = Wt + 2097152;            // [512][2048]
    bf16* bqvr = Wt + 3145728;
    bf16* bob  = Wt + 3147264;
    bf16* bf1b = Wt + 3147776;
    bf16* bf2b = Wt + 3149824;

    dim3 blk(256);
    probe_kernel<<<1, blk, 0, stream>>>(x, flag);
    convert_x<<<4096, blk, 0, stream>>>(x, xb, flag);
    prep_weights<<<12306, blk, 0, stream>>>(
        d_in[1], d_in[3], d_in[5], d_in[8], d_in[12], d_in[14],
        d_in[2], d_in[4], d_in[6], d_in[9], d_in[13], d_in[15],
        Wqvr, Wob, Wf1t, Wf2t, bqvr, bob, bf1b, bf2b, flag);

    // fused Q|V|R projection: [16384,512] x [1536,512]^T -> QVR (ldc 1536)
    mfma_gemm<false><<<dim3(128, 12), blk, 0, stream>>>(xb, Wqvr, bqvr, QVR, 512, 512, 1536);

    // recurrence in place on R slice
    recur_kernel<<<16, blk, 0, stream>>>(QVR, d_in[7], flag);

    // attention
    attn_mfma<<<dim3(16, 64), blk, 0, stream>>>(QVR, Ob);

    // Wo projection
    mfma_gemm<false><<<dim3(128, 4), blk, 0, stream>>>(Ob, Wob, bob, AO, 512, 512, 512);

    // LN1
    ln1_kernel<<<MROWS, blk, 0, stream>>>(xb, AO, d_in[10], d_in[11], X1, flag);

    // FF1 (relu)
    mfma_gemm<true><<<dim3(128, 16), blk, 0, stream>>>(X1, Wf1t, bf1b, FFH, 512, 512, 2048);

    // FF2
    mfma_gemm<false><<<dim3(128, 4), blk, 0, stream>>>(FFH, Wf2t, bf2b, FF2, 2048, 2048, 512);

    // LN2 -> d_out
    ln2_kernel<<<MROWS, blk, 0, stream>>>(X1, FF2, d_in[16], d_in[17], d_out, flag);
}

// Round 4
// 788.465 us; speedup vs baseline: 5.6500x; 1.4602x over previous
//
#include <hip/hip_runtime.h>
#include <hip/hip_bf16.h>
#include <math.h>

#define SEQ    2048
#define BATCH  8
#define DMODEL 512
#define NHEADS 8
#define DK     64
#define DFF    2048
#define MROWS  16384

typedef __hip_bfloat16 bf16;
typedef unsigned int   u32;
typedef unsigned short u16;
typedef __attribute__((ext_vector_type(8))) short short8;   // 8 bf16 = 4 VGPR
typedef __attribute__((ext_vector_type(4))) float f32x4;

__device__ __forceinline__ float b2f(bf16 v) { return __bfloat162float(v); }
__device__ __forceinline__ bf16  f2b(float f) { return __float2bfloat16(f); }
__device__ __forceinline__ u16 f2u(float f) { bf16 h = __float2bfloat16(f); return *(u16*)&h; }
__device__ __forceinline__ u32 pack2(float a, float b) {
    return ((u32)f2u(b) << 16) | (u32)f2u(a);
}
// external-tensor load: dtype decided at runtime by probe flag (0=bf16, 1=fp32)
__device__ __forceinline__ float ldE(const void* p, long off, int f32) {
    return f32 ? ((const float*)p)[off] : b2f(((const bf16*)p)[off]);
}
// async global->LDS, 16B per lane; lds base must be wave-uniform
__device__ __forceinline__ void async16(bf16* lds, const bf16* g) {
    __builtin_amdgcn_global_load_lds(
        (const __attribute__((address_space(1))) void*)g,
        (__attribute__((address_space(3))) void*)lds, 16, 0, 0);
}

// ---------------------------------------------------------------------------
// Dtype probe (verified round 2): flag=1 means fp32 inputs.
// ---------------------------------------------------------------------------
__global__ __launch_bounds__(256) void probe_kernel(const void* __restrict__ x,
                                                    int* __restrict__ flag)
{
    int tid = threadIdx.x;
    const u16* u = (const u16*)x;
    int cnt = 0;
    #pragma unroll
    for (int i = 0; i < 8; i++) {
        u16 e = u[tid * 8 + i];
        float v = __uint_as_float(((u32)e) << 16);
        float a = fabsf(v);
        if (a > 9.313226e-10f && a < 1.0737418e9f) cnt++;
    }
    __shared__ int sh[256];
    sh[tid] = cnt;
    __syncthreads();
    for (int s = 128; s > 0; s >>= 1) {
        if (tid < s) sh[tid] += sh[tid + s];
        __syncthreads();
    }
    if (tid == 0) *flag = (sh[0] < 1700) ? 1 : 0;
}

// ---------------------------------------------------------------------------
// x (S,B,D) external dtype -> xb bf16 plain [b*SEQ+s][512]
// ---------------------------------------------------------------------------
__global__ __launch_bounds__(256) void convert_x(const void* __restrict__ x,
                                                 bf16* __restrict__ xb,
                                                 const int* __restrict__ flagp)
{
    const int f32 = *flagp;
    int gid = blockIdx.x * 256 + threadIdx.x;      // 0..1048575
    int row_in = gid >> 6;                         // s*8+b
    int d8 = (gid & 63) * 8;
    int s = row_in >> 3, b = row_in & 7;
    long src = (long)row_in * 512 + d8;
    long dst = ((long)b * SEQ + s) * 512 + d8;
    if (f32) {
        const float* xf = (const float*)x;
        float4 a = *(const float4*)(xf + src);
        float4 c = *(const float4*)(xf + src + 4);
        u32 o[4] = { pack2(a.x,a.y), pack2(a.z,a.w), pack2(c.x,c.y), pack2(c.z,c.w) };
        *(uint4*)(xb + dst) = *(uint4*)o;
    } else {
        *(uint4*)(xb + dst) = *(const uint4*)((const bf16*)x + src);
    }
}

// ---------------------------------------------------------------------------
// Pack/convert all weights to bf16 [N][K] form.
// ---------------------------------------------------------------------------
__global__ __launch_bounds__(256) void prep_weights(
    const void* Wq, const void* Wv, const void* Wr, const void* Wo,
    const void* Wf1, const void* Wf2,
    const void* bq, const void* bv, const void* br, const void* bo,
    const void* bf1, const void* bf2,
    bf16* __restrict__ Wqvr, bf16* __restrict__ Wob,
    bf16* __restrict__ Wf1t, bf16* __restrict__ Wf2t,
    bf16* __restrict__ bqvr, bf16* __restrict__ bob,
    bf16* __restrict__ bf1b, bf16* __restrict__ bf2b,
    const int* __restrict__ flagp)
{
    const int f32 = *flagp;
    long g = (long)blockIdx.x * 256 + threadIdx.x;   // < 3150336
    if (g < 786432) {
        const void* src = (g < 262144) ? Wq : (g < 524288) ? Wv : Wr;
        long j = g & 262143;
        Wqvr[g] = f2b(ldE(src, j, f32));
    } else if (g < 1048576) {
        long j = g - 786432;
        Wob[j] = f2b(ldE(Wo, j, f32));
    } else if (g < 2097152) {
        long j = g - 1048576;
        long n = j >> 9, k = j & 511;
        Wf1t[j] = f2b(ldE(Wf1, k * 2048 + n, f32));
    } else if (g < 3145728) {
        long j = g - 2097152;
        long n = j >> 11, k = j & 2047;
        Wf2t[j] = f2b(ldE(Wf2, k * 512 + n, f32));
    } else {
        long j = g - 3145728;
        if (j < 512)       bqvr[j]      = f2b(ldE(bq, j, f32));
        else if (j < 1024) bqvr[j]      = f2b(ldE(bv, j - 512, f32));
        else if (j < 1536) bqvr[j]      = f2b(ldE(br, j - 1024, f32));
        else if (j < 2048) bob[j-1536]  = f2b(ldE(bo, j - 1536, f32));
        else if (j < 4096) bf1b[j-2048] = f2b(ldE(bf1, j - 2048, f32));
        else if (j < 4608) bf2b[j-4096] = f2b(ldE(bf2, j - 4096, f32));
    }
}

// ---------------------------------------------------------------------------
// MFMA GEMM (m97 structure): C[m][n] = sum_k A[m][k]*W[n][k] + bias[n]
// 128x128 tile, BK=32, 256 thr = 4 waves (2x2), 4x4 16x16 tiles per wave.
// ---------------------------------------------------------------------------
template<bool RELU>
__global__ __launch_bounds__(256) void mfma_gemm(
    const bf16* __restrict__ A, const bf16* __restrict__ W,
    const bf16* __restrict__ bias, bf16* __restrict__ C,
    int K, int lda, int ldc)
{
    __shared__ bf16 As[128 * 32];
    __shared__ bf16 Bs[128 * 32];
    const int tid = threadIdx.x;
    const int w = tid >> 6, lane = tid & 63;
    const int li = lane & 15, quad = lane >> 4;
    const int m0 = blockIdx.x * 128, n0 = blockIdx.y * 128;
    const int wm = (w >> 1) * 64, wn = (w & 1) * 64;
    const int srow = lane >> 2, scol = (lane & 3) * 8;

    f32x4 acc[4][4];
    const f32x4 z4 = {0.f, 0.f, 0.f, 0.f};
    #pragma unroll
    for (int i = 0; i < 4; i++)
        #pragma unroll
        for (int j = 0; j < 4; j++) acc[i][j] = z4;

    const bf16* ga = A + (long)(m0 + w * 32 + srow) * lda + scol;
    const bf16* gb = W + (long)(n0 + w * 32 + srow) * K + scol;
    bf16* lA0 = &As[(w * 32) * 32];
    bf16* lA1 = &As[(w * 32 + 16) * 32];
    bf16* lB0 = &Bs[(w * 32) * 32];
    bf16* lB1 = &Bs[(w * 32 + 16) * 32];

    for (int k0 = 0; k0 < K; k0 += 32) {
        __syncthreads();
        async16(lA0, ga);
        async16(lA1, ga + (long)16 * lda);
        async16(lB0, gb);
        async16(lB1, gb + (long)16 * K);
        ga += 32; gb += 32;
        __syncthreads();
        short8 af[4], bfr[4];
        #pragma unroll
        for (int t = 0; t < 4; t++)
            af[t] = *(const short8*)&As[(wm + t * 16 + li) * 32 + quad * 8];
        #pragma unroll
        for (int t = 0; t < 4; t++)
            bfr[t] = *(const short8*)&Bs[(wn + t * 16 + li) * 32 + quad * 8];
        #pragma unroll
        for (int i = 0; i < 4; i++)
            #pragma unroll
            for (int j = 0; j < 4; j++)
                acc[i][j] = __builtin_amdgcn_mfma_f32_16x16x32_bf16(
                    af[i], bfr[j], acc[i][j], 0, 0, 0);
    }

    #pragma unroll
    for (int i = 0; i < 4; i++) {
        #pragma unroll
        for (int j = 0; j < 4; j++) {
            int col = n0 + wn + j * 16 + li;
            float bb = b2f(bias[col]);
            #pragma unroll
            for (int r = 0; r < 4; r++) {
                int row = m0 + wm + i * 16 + quad * 4 + r;
                float v = acc[i][j][r] + bb;
                if (RELU) v = fmaxf(v, 0.f);
                C[(long)row * ldc + col] = f2b(v);
            }
        }
    }
}

// ---------------------------------------------------------------------------
// Recurrence on the R slice of QVR (cols 1024..1536, row stride 1536).
// Latency-optimized: r-stream prefetched 32 deep (double-buffered chunks,
// pre-scaled by 2*log2e off the critical chain); dependent chain is
// fma -> v_exp_f32 -> add -> v_rcp_f32 -> fma via the overflow-safe identity
// tanh(x) = 1 - 2/(exp2(2*log2e*x)+1)   (e=inf -> 1, e=0 -> -1).
// ---------------------------------------------------------------------------
#define LOG2E2 2.8853900817779268f   // 2*log2(e)
__global__ __launch_bounds__(256) void recur_kernel(bf16* __restrict__ QVR,
                                                    const void* __restrict__ Wh,
                                                    const int* __restrict__ flagp)
{
    const int f32 = *flagp;
    int idx = blockIdx.x * 256 + threadIdx.x;   // 0 .. 4095
    int b = idx >> 9, o = idx & 511;
    float w = 0.0f;
    #pragma unroll
    for (int k = 0; k < DK; k++) w += ldE(Wh, (long)o * DK + k, f32);
    const float w2 = w * LOG2E2;
    bf16* base = QVR + (long)b * SEQ * 1536 + 1024 + o;

    const int PF = 32;
    float buf[PF];
    #pragma unroll
    for (int i = 0; i < PF; i++)
        buf[i] = b2f(base[(long)i * 1536]) * LOG2E2;

    float h = 0.0f;
    for (int s = 0; s < SEQ; s += PF) {
        float nbuf[PF];
        if (s + PF < SEQ) {
            #pragma unroll
            for (int i = 0; i < PF; i++)
                nbuf[i] = b2f(base[(long)(s + PF + i) * 1536]) * LOG2E2;
        }
        #pragma unroll
        for (int i = 0; i < PF; i++) {
            float xx = fmaf(h, w2, buf[i]);            // 2*log2e*(h*w + r)
            float e  = exp2f(xx);                      // v_exp_f32
            float d  = __builtin_amdgcn_rcpf(e + 1.0f);
            h = fmaf(-2.0f, d, 1.0f);                  // tanh
            base[(long)(s + i) * 1536] = f2b(h);       // store off-chain
        }
        #pragma unroll
        for (int i = 0; i < PF; i++) buf[i] = nbuf[i];
    }
}

// ---------------------------------------------------------------------------
// MFMA flash attention (unchanged from round 3).
// ---------------------------------------------------------------------------
__global__ __launch_bounds__(256) void attn_mfma(const bf16* __restrict__ QVR,
                                                 bf16* __restrict__ O)
{
    __shared__ bf16 Kt[64 * 72];          // [key][d], pad 8
    __shared__ bf16 Vt[64 * 72];          // [d][key], pad 8
    __shared__ bf16 Pl[4 * 32 * 72];      // per-wave P [qrow][key], pad 8
    const int tid = threadIdx.x;
    const int w = tid >> 6, lane = tid & 63;
    const int li = lane & 15, quad = lane >> 4;
    const int b = blockIdx.y >> 3, hd = blockIdx.y & 7;
    const int q0 = blockIdx.x * 128;
    const long rowb = (long)b * SEQ;
    const bf16* Qb = QVR + hd * DK;
    const bf16* Hb = QVR + 1024 + hd * DK;
    const bf16* Vb = QVR + 512 + hd * DK;
    bf16* Pw = &Pl[w * 32 * 72];
    const f32x4 z4 = {0.f, 0.f, 0.f, 0.f};

    short8 qa[2][2];
    #pragma unroll
    for (int mt = 0; mt < 2; mt++)
        #pragma unroll
        for (int ks = 0; ks < 2; ks++)
            qa[mt][ks] = *(const short8*)&Qb[(rowb + q0 + w * 32 + mt * 16 + li) * 1536
                                             + ks * 32 + quad * 8];

    f32x4 oacc[2][4];
    float m_run[2][4], l_run[2][4];
    #pragma unroll
    for (int mt = 0; mt < 2; mt++) {
        #pragma unroll
        for (int dt = 0; dt < 4; dt++) oacc[mt][dt] = z4;
        #pragma unroll
        for (int r = 0; r < 4; r++) { m_run[mt][r] = -1e30f; l_run[mt][r] = 0.f; }
    }

    for (int kt = 0; kt < SEQ; kt += 64) {
        __syncthreads();
        #pragma unroll
        for (int i = 0; i < 2; i++) {
            int r = (tid >> 3) + i * 32;
            int c8 = (tid & 7) * 8;
            long goff = (rowb + kt + r) * 1536 + c8;
            uint4 hv = *(const uint4*)&Hb[goff];
            *(uint4*)&Kt[r * 72 + c8] = hv;
            uint4 vv = *(const uint4*)&Vb[goff];
            bf16 tmp[8];
            *(uint4*)tmp = vv;
            #pragma unroll
            for (int j = 0; j < 8; j++) Vt[(c8 + j) * 72 + r] = tmp[j];
        }
        __syncthreads();

        // ---- S = Q K^T ----
        f32x4 sa[2][4];
        #pragma unroll
        for (int mt = 0; mt < 2; mt++)
            #pragma unroll
            for (int nt = 0; nt < 4; nt++) sa[mt][nt] = z4;
        #pragma unroll
        for (int ks = 0; ks < 2; ks++) {
            short8 kb[4];
            #pragma unroll
            for (int nt = 0; nt < 4; nt++)
                kb[nt] = *(const short8*)&Kt[(nt * 16 + li) * 72 + ks * 32 + quad * 8];
            #pragma unroll
            for (int mt = 0; mt < 2; mt++)
                #pragma unroll
                for (int nt = 0; nt < 4; nt++)
                    sa[mt][nt] = __builtin_amdgcn_mfma_f32_16x16x32_bf16(
                        qa[mt][ks], kb[nt], sa[mt][nt], 0, 0, 0);
        }

        // ---- online softmax ----
        #pragma unroll
        for (int mt = 0; mt < 2; mt++) {
            #pragma unroll
            for (int r = 0; r < 4; r++) {
                int qrow = q0 + w * 32 + mt * 16 + quad * 4 + r;
                float mval = -1e30f;
                #pragma unroll
                for (int nt = 0; nt < 4; nt++) {
                    int key = kt + nt * 16 + li;
                    float s = sa[mt][nt][r] * 0.125f + ((key > qrow) ? 1.0f : 0.0f);
                    sa[mt][nt][r] = s;
                    mval = fmaxf(mval, s);
                }
                #pragma unroll
                for (int d = 1; d < 16; d <<= 1) mval = fmaxf(mval, __shfl_xor(mval, d));
                float mnew = fmaxf(m_run[mt][r], mval);
                float alpha = __expf(m_run[mt][r] - mnew);
                m_run[mt][r] = mnew;
                float rs = 0.f;
                #pragma unroll
                for (int nt = 0; nt < 4; nt++) {
                    float p = __expf(sa[mt][nt][r] - mnew);
                    rs += p;
                    Pw[(mt * 16 + quad * 4 + r) * 72 + nt * 16 + li] = f2b(p);
                }
                #pragma unroll
                for (int d = 1; d < 16; d <<= 1) rs += __shfl_xor(rs, d);
                l_run[mt][r] = l_run[mt][r] * alpha + rs;
                #pragma unroll
                for (int dt = 0; dt < 4; dt++) oacc[mt][dt][r] *= alpha;
            }
        }

        // ---- O += P V ----
        #pragma unroll
        for (int ks = 0; ks < 2; ks++) {
            short8 vbf[4], pa[2];
            #pragma unroll
            for (int dt = 0; dt < 4; dt++)
                vbf[dt] = *(const short8*)&Vt[(dt * 16 + li) * 72 + ks * 32 + quad * 8];
            #pragma unroll
            for (int mt = 0; mt < 2; mt++)
                pa[mt] = *(const short8*)&Pw[(mt * 16 + li) * 72 + ks * 32 + quad * 8];
            #pragma unroll
            for (int mt = 0; mt < 2; mt++)
                #pragma unroll
                for (int dt = 0; dt < 4; dt++)
                    oacc[mt][dt] = __builtin_amdgcn_mfma_f32_16x16x32_bf16(
                        pa[mt], vbf[dt], oacc[mt][dt], 0, 0, 0);
        }
    }

    #pragma unroll
    for (int mt = 0; mt < 2; mt++)
        #pragma unroll
        for (int r = 0; r < 4; r++) {
            float inv = 1.0f / l_run[mt][r];
            long row = rowb + q0 + w * 32 + mt * 16 + quad * 4 + r;
            #pragma unroll
            for (int dt = 0; dt < 4; dt++)
                O[row * 512 + hd * 64 + dt * 16 + li] = f2b(oacc[mt][dt][r] * inv);
        }
}

// ---------------------------------------------------------------------------
// LN1: xb + AO (both bf16 plain) -> X1 bf16 plain
// ---------------------------------------------------------------------------
__global__ __launch_bounds__(256) void ln1_kernel(const bf16* __restrict__ xb,
                                                  const bf16* __restrict__ ao,
                                                  const void* __restrict__ g,
                                                  const void* __restrict__ beta,
                                                  bf16* __restrict__ x1,
                                                  const int* __restrict__ flagp)
{
    const int f32 = *flagp;
    long base = (long)blockIdx.x * 512;
    int tid = threadIdx.x;
    float v[2];
    #pragma unroll
    for (int i = 0; i < 2; i++) {
        int d = tid + i * 256;
        v[i] = b2f(xb[base + d]) + b2f(ao[base + d]);
    }
    float s1 = v[0] + v[1];
    float s2 = v[0] * v[0] + v[1] * v[1];
    #pragma unroll
    for (int off = 32; off > 0; off >>= 1) {
        s1 += __shfl_down(s1, off);
        s2 += __shfl_down(s2, off);
    }
    __shared__ float w1[4], w2[4];
    int wid = tid >> 6, lane = tid & 63;
    if (lane == 0) { w1[wid] = s1; w2[wid] = s2; }
    __syncthreads();
    float t1 = w1[0] + w1[1] + w1[2] + w1[3];
    float t2 = w2[0] + w2[1] + w2[2] + w2[3];
    float mu = t1 * (1.0f / DMODEL);
    float var = t2 * (1.0f / DMODEL) - mu * mu;
    float rs = rsqrtf(var + 1e-5f);
    #pragma unroll
    for (int i = 0; i < 2; i++) {
        int d = tid + i * 256;
        x1[base + d] = f2b((v[i] - mu) * rs * ldE(g, d, f32) + ldE(beta, d, f32));
    }
}

// ---------------------------------------------------------------------------
// LN2: X1 + FF2 -> d_out (external dtype, (S,B,D) layout)
// ---------------------------------------------------------------------------
__global__ __launch_bounds__(256) void ln2_kernel(const bf16* __restrict__ x1,
                                                  const bf16* __restrict__ ff2,
                                                  const void* __restrict__ g,
                                                  const void* __restrict__ beta,
                                                  void* __restrict__ outp,
                                                  const int* __restrict__ flagp)
{
    const int f32 = *flagp;
    int m = blockIdx.x;                 // b*SEQ + s
    int b = m >> 11, s = m & 2047;
    long plain = (long)m * 512;
    long funny = ((long)s * BATCH + b) * 512;
    int tid = threadIdx.x;
    float v[2];
    #pragma unroll
    for (int i = 0; i < 2; i++) {
        int d = tid + i * 256;
        v[i] = b2f(x1[plain + d]) + b2f(ff2[plain + d]);
    }
    float s1 = v[0] + v[1];
    float s2 = v[0] * v[0] + v[1] * v[1];
    #pragma unroll
    for (int off = 32; off > 0; off >>= 1) {
        s1 += __shfl_down(s1, off);
        s2 += __shfl_down(s2, off);
    }
    __shared__ float w1[4], w2[4];
    int wid = tid >> 6, lane = tid & 63;
    if (lane == 0) { w1[wid] = s1; w2[wid] = s2; }
    __syncthreads();
    float t1 = w1[0] + w1[1] + w1[2] + w1[3];
    float t2 = w2[0] + w2[1] + w2[2] + w2[3];
    float mu = t1 * (1.0f / DMODEL);
    float var = t2 * (1.0f / DMODEL) - mu * mu;
    float rs = rsqrtf(var + 1e-5f);
    #pragma unroll
    for (int i = 0; i < 2; i++) {
        int d = tid + i * 256;
        float r = (v[i] - mu) * rs * ldE(g, d, f32) + ldE(beta, d, f32);
        if (f32) ((float*)outp)[funny + d] = r;
        else     ((bf16*)outp)[funny + d] = f2b(r);
    }
}

// ---------------------------------------------------------------------------
extern "C" void kernel_launch(void* const* d_in, const int* in_sizes, int n_in,
                              void* d_out, int out_size, void* d_ws, size_t ws_size,
                              hipStream_t stream)
{
    (void)in_sizes; (void)n_in; (void)out_size; (void)ws_size;
    const void* x = d_in[0];

    // bf16 workspace layout (elements):
    bf16* W    = (bf16*)d_ws;
    bf16* xb   = W;                       // [0, 8M)   dead after LN1
    bf16* QVR  = W + (8u  << 20);         // [8M, 32M) Q|V|R cols, dead after attn
    bf16* Ob   = W + (32u << 20);         // [32M,40M) dead after Wo gemm
    bf16* AO   = W + (40u << 20);         // [40M,48M) dead after LN1
    bf16* X1   = W + (8u  << 20);         // reuse QVR head, alive until LN2
    bf16* FFH  = W + (16u << 20);         // [16M,48M) after LN1
    bf16* FF2  = W;                       // reuse xb
    int*  flag = (int*)((char*)d_ws + (size_t)96 * 1024 * 1024);
    bf16* Wt   = (bf16*)((char*)d_ws + (size_t)96 * 1024 * 1024 + 16);
    bf16* Wqvr = Wt;                      // [1536][512]
    bf16* Wob  = Wt + 786432;             // [512][512]
    bf16* Wf1t = Wt + 1048576;            // [2048][512]
    bf16* Wf2t = Wt + 2097152;            // [512][2048]
    bf16* bqvr = Wt + 3145728;
    bf16* bob  = Wt + 3147264;
    bf16* bf1b = Wt + 3147776;
    bf16* bf2b = Wt + 3149824;

    dim3 blk(256);
    probe_kernel<<<1, blk, 0, stream>>>(x, flag);
    convert_x<<<4096, blk, 0, stream>>>(x, xb, flag);
    prep_weights<<<12306, blk, 0, stream>>>(
        d_in[1], d_in[3], d_in[5], d_in[8], d_in[12], d_in[14],
        d_in[2], d_in[4], d_in[6], d_in[9], d_in[13], d_in[15],
        Wqvr, Wob, Wf1t, Wf2t, bqvr, bob, bf1b, bf2b, flag);

    // fused Q|V|R projection: [16384,512] x [1536,512]^T -> QVR (ldc 1536)
    mfma_gemm<false><<<dim3(128, 12), blk, 0, stream>>>(xb, Wqvr, bqvr, QVR, 512, 512, 1536);

    // recurrence in place on R slice
    recur_kernel<<<16, blk, 0, stream>>>(QVR, d_in[7], flag);

    // attention
    attn_mfma<<<dim3(16, 64), blk, 0, stream>>>(QVR, Ob);

    // Wo projection
    mfma_gemm<false><<<dim3(128, 4), blk, 0, stream>>>(Ob, Wob, bob, AO, 512, 512, 512);

    // LN1
    ln1_kernel<<<MROWS, blk, 0, stream>>>(xb, AO, d_in[10], d_in[11], X1, flag);

    // FF1 (relu)
    mfma_gemm<true><<<dim3(128, 16), blk, 0, stream>>>(X1, Wf1t, bf1b, FFH, 512, 512, 2048);

    // FF2
    mfma_gemm<false><<<dim3(128, 4), blk, 0, stream>>>(FFH, Wf2t, bf2b, FF2, 2048, 2048, 512);

    // LN2 -> d_out
    ln2_kernel<<<MROWS, blk, 0, stream>>>(X1, FF2, d_in[16], d_in[17], d_out, flag);
}

// Round 5
// 630.601 us; speedup vs baseline: 7.0644x; 1.2503x over previous
//
#include <hip/hip_runtime.h>
#include <hip/hip_bf16.h>
#include <math.h>

#define SEQ    2048
#define BATCH  8
#define DMODEL 512
#define NHEADS 8
#define DK     64
#define DFF    2048
#define MROWS  16384

typedef __hip_bfloat16 bf16;
typedef unsigned int   u32;
typedef unsigned short u16;
typedef __attribute__((ext_vector_type(8))) short short8;   // 8 bf16 = 4 VGPR
typedef __attribute__((ext_vector_type(4))) float f32x4;

__device__ __forceinline__ float b2f(bf16 v) { return __bfloat162float(v); }
__device__ __forceinline__ bf16  f2b(float f) { return __float2bfloat16(f); }
__device__ __forceinline__ u16 f2u(float f) { bf16 h = __float2bfloat16(f); return *(u16*)&h; }
__device__ __forceinline__ u32 pack2(float a, float b) {
    return ((u32)f2u(b) << 16) | (u32)f2u(a);
}
// external-tensor load: dtype decided at runtime by probe flag (0=bf16, 1=fp32)
__device__ __forceinline__ float ldE(const void* p, long off, int f32) {
    return f32 ? ((const float*)p)[off] : b2f(((const bf16*)p)[off]);
}
// async global->LDS, 16B per lane; lds base must be wave-uniform
__device__ __forceinline__ void async16(bf16* lds, const bf16* g) {
    __builtin_amdgcn_global_load_lds(
        (const __attribute__((address_space(1))) void*)g,
        (__attribute__((address_space(3))) void*)lds, 16, 0, 0);
}

// ---------------------------------------------------------------------------
// Dtype probe (verified round 2): flag=1 means fp32 inputs.
// ---------------------------------------------------------------------------
__global__ __launch_bounds__(256) void probe_kernel(const void* __restrict__ x,
                                                    int* __restrict__ flag)
{
    int tid = threadIdx.x;
    const u16* u = (const u16*)x;
    int cnt = 0;
    #pragma unroll
    for (int i = 0; i < 8; i++) {
        u16 e = u[tid * 8 + i];
        float v = __uint_as_float(((u32)e) << 16);
        float a = fabsf(v);
        if (a > 9.313226e-10f && a < 1.0737418e9f) cnt++;
    }
    __shared__ int sh[256];
    sh[tid] = cnt;
    __syncthreads();
    for (int s = 128; s > 0; s >>= 1) {
        if (tid < s) sh[tid] += sh[tid + s];
        __syncthreads();
    }
    if (tid == 0) *flag = (sh[0] < 1700) ? 1 : 0;
}

// ---------------------------------------------------------------------------
// x (S,B,D) external dtype -> xb bf16 plain [b*SEQ+s][512]
// ---------------------------------------------------------------------------
__global__ __launch_bounds__(256) void convert_x(const void* __restrict__ x,
                                                 bf16* __restrict__ xb,
                                                 const int* __restrict__ flagp)
{
    const int f32 = *flagp;
    int gid = blockIdx.x * 256 + threadIdx.x;      // 0..1048575
    int row_in = gid >> 6;                         // s*8+b
    int d8 = (gid & 63) * 8;
    int s = row_in >> 3, b = row_in & 7;
    long src = (long)row_in * 512 + d8;
    long dst = ((long)b * SEQ + s) * 512 + d8;
    if (f32) {
        const float* xf = (const float*)x;
        float4 a = *(const float4*)(xf + src);
        float4 c = *(const float4*)(xf + src + 4);
        u32 o[4] = { pack2(a.x,a.y), pack2(a.z,a.w), pack2(c.x,c.y), pack2(c.z,c.w) };
        *(uint4*)(xb + dst) = *(uint4*)o;
    } else {
        *(uint4*)(xb + dst) = *(const uint4*)((const bf16*)x + src);
    }
}

// ---------------------------------------------------------------------------
// Pack/convert all weights to bf16 [N][K] form.
// ---------------------------------------------------------------------------
__global__ __launch_bounds__(256) void prep_weights(
    const void* Wq, const void* Wv, const void* Wr, const void* Wo,
    const void* Wf1, const void* Wf2,
    const void* bq, const void* bv, const void* br, const void* bo,
    const void* bf1, const void* bf2,
    bf16* __restrict__ Wqvr, bf16* __restrict__ Wob,
    bf16* __restrict__ Wf1t, bf16* __restrict__ Wf2t,
    bf16* __restrict__ bqvr, bf16* __restrict__ bob,
    bf16* __restrict__ bf1b, bf16* __restrict__ bf2b,
    const int* __restrict__ flagp)
{
    const int f32 = *flagp;
    long g = (long)blockIdx.x * 256 + threadIdx.x;   // < 3150336
    if (g < 786432) {
        const void* src = (g < 262144) ? Wq : (g < 524288) ? Wv : Wr;
        long j = g & 262143;
        Wqvr[g] = f2b(ldE(src, j, f32));
    } else if (g < 1048576) {
        long j = g - 786432;
        Wob[j] = f2b(ldE(Wo, j, f32));
    } else if (g < 2097152) {
        long j = g - 1048576;
        long n = j >> 9, k = j & 511;
        Wf1t[j] = f2b(ldE(Wf1, k * 2048 + n, f32));
    } else if (g < 3145728) {
        long j = g - 2097152;
        long n = j >> 11, k = j & 2047;
        Wf2t[j] = f2b(ldE(Wf2, k * 512 + n, f32));
    } else {
        long j = g - 3145728;
        if (j < 512)       bqvr[j]      = f2b(ldE(bq, j, f32));
        else if (j < 1024) bqvr[j]      = f2b(ldE(bv, j - 512, f32));
        else if (j < 1536) bqvr[j]      = f2b(ldE(br, j - 1024, f32));
        else if (j < 2048) bob[j-1536]  = f2b(ldE(bo, j - 1536, f32));
        else if (j < 4096) bf1b[j-2048] = f2b(ldE(bf1, j - 2048, f32));
        else if (j < 4608) bf2b[j-4096] = f2b(ldE(bf2, j - 4096, f32));
    }
}

// ---------------------------------------------------------------------------
// MFMA GEMM (m97 structure): C[m][n] = sum_k A[m][k]*W[n][k] + bias[n]
// ---------------------------------------------------------------------------
template<bool RELU>
__global__ __launch_bounds__(256) void mfma_gemm(
    const bf16* __restrict__ A, const bf16* __restrict__ W,
    const bf16* __restrict__ bias, bf16* __restrict__ C,
    int K, int lda, int ldc)
{
    __shared__ bf16 As[128 * 32];
    __shared__ bf16 Bs[128 * 32];
    const int tid = threadIdx.x;
    const int w = tid >> 6, lane = tid & 63;
    const int li = lane & 15, quad = lane >> 4;
    const int m0 = blockIdx.x * 128, n0 = blockIdx.y * 128;
    const int wm = (w >> 1) * 64, wn = (w & 1) * 64;
    const int srow = lane >> 2, scol = (lane & 3) * 8;

    f32x4 acc[4][4];
    const f32x4 z4 = {0.f, 0.f, 0.f, 0.f};
    #pragma unroll
    for (int i = 0; i < 4; i++)
        #pragma unroll
        for (int j = 0; j < 4; j++) acc[i][j] = z4;

    const bf16* ga = A + (long)(m0 + w * 32 + srow) * lda + scol;
    const bf16* gb = W + (long)(n0 + w * 32 + srow) * K + scol;
    bf16* lA0 = &As[(w * 32) * 32];
    bf16* lA1 = &As[(w * 32 + 16) * 32];
    bf16* lB0 = &Bs[(w * 32) * 32];
    bf16* lB1 = &Bs[(w * 32 + 16) * 32];

    for (int k0 = 0; k0 < K; k0 += 32) {
        __syncthreads();
        async16(lA0, ga);
        async16(lA1, ga + (long)16 * lda);
        async16(lB0, gb);
        async16(lB1, gb + (long)16 * K);
        ga += 32; gb += 32;
        __syncthreads();
        short8 af[4], bfr[4];
        #pragma unroll
        for (int t = 0; t < 4; t++)
            af[t] = *(const short8*)&As[(wm + t * 16 + li) * 32 + quad * 8];
        #pragma unroll
        for (int t = 0; t < 4; t++)
            bfr[t] = *(const short8*)&Bs[(wn + t * 16 + li) * 32 + quad * 8];
        #pragma unroll
        for (int i = 0; i < 4; i++)
            #pragma unroll
            for (int j = 0; j < 4; j++)
                acc[i][j] = __builtin_amdgcn_mfma_f32_16x16x32_bf16(
                    af[i], bfr[j], acc[i][j], 0, 0, 0);
    }

    #pragma unroll
    for (int i = 0; i < 4; i++) {
        #pragma unroll
        for (int j = 0; j < 4; j++) {
            int col = n0 + wn + j * 16 + li;
            float bb = b2f(bias[col]);
            #pragma unroll
            for (int r = 0; r < 4; r++) {
                int row = m0 + wm + i * 16 + quad * 4 + r;
                float v = acc[i][j][r] + bb;
                if (RELU) v = fmaxf(v, 0.f);
                C[(long)row * ldc + col] = f2b(v);
            }
        }
    }
}

// ---------------------------------------------------------------------------
// Recurrence (latency-optimized, verified round 4).
// ---------------------------------------------------------------------------
#define LOG2E2 2.8853900817779268f   // 2*log2(e)
__global__ __launch_bounds__(256) void recur_kernel(bf16* __restrict__ QVR,
                                                    const void* __restrict__ Wh,
                                                    const int* __restrict__ flagp)
{
    const int f32 = *flagp;
    int idx = blockIdx.x * 256 + threadIdx.x;   // 0 .. 4095
    int b = idx >> 9, o = idx & 511;
    float w = 0.0f;
    #pragma unroll
    for (int k = 0; k < DK; k++) w += ldE(Wh, (long)o * DK + k, f32);
    const float w2 = w * LOG2E2;
    bf16* base = QVR + (long)b * SEQ * 1536 + 1024 + o;

    const int PF = 32;
    float buf[PF];
    #pragma unroll
    for (int i = 0; i < PF; i++)
        buf[i] = b2f(base[(long)i * 1536]) * LOG2E2;

    float h = 0.0f;
    for (int s = 0; s < SEQ; s += PF) {
        float nbuf[PF];
        if (s + PF < SEQ) {
            #pragma unroll
            for (int i = 0; i < PF; i++)
                nbuf[i] = b2f(base[(long)(s + PF + i) * 1536]) * LOG2E2;
        }
        #pragma unroll
        for (int i = 0; i < PF; i++) {
            float xx = fmaf(h, w2, buf[i]);            // 2*log2e*(h*w + r)
            float e  = exp2f(xx);                      // v_exp_f32
            float d  = __builtin_amdgcn_rcpf(e + 1.0f);
            h = fmaf(-2.0f, d, 1.0f);                  // tanh
            base[(long)(s + i) * 1536] = f2b(h);       // store off-chain
        }
        #pragma unroll
        for (int i = 0; i < PF; i++) buf[i] = nbuf[i];
    }
}

// ---------------------------------------------------------------------------
// MFMA flash attention, round-5 rewrite:
//  * no-max softmax (scores bounded: H in (-1,1), scale 1/8, mask +1 ->
//    |s| <= ~10, exp2 can't overflow fp32); l accumulated per-lane,
//    reduced across the 16-lane group ONCE after the K-loop.
//  * wave-uniform mask classes (none/all/mixed) -- per-element cmp only on
//    the <=2 mixed tiles per wave.
//  * K/H tile: 2 unpadded panels [ks][64key][32d] via global_load_lds
//    (identical read pattern to the proven GEMM A-tile).
//  * V^T tile: 2 panels [ks][64d][32key] with XOR-swizzled key index
//    ((key&31) ^ ((d>>3&3)<<3)) -- scatter writes ~2-way instead of 8-way,
//    b128 reads stay aligned+contiguous (swizzle permutes aligned 8-groups).
//  * P keeps the verified LDS round-trip (Pl, pad 72).
// ---------------------------------------------------------------------------
#define SC2 0.18033688011112042f     // 0.125 * log2(e)
#define MC2 1.4426950408889634f      // log2(e)
__global__ __launch_bounds__(256) void attn_mfma(const bf16* __restrict__ QVR,
                                                 bf16* __restrict__ O)
{
    __shared__ bf16 Kt[2 * 64 * 32];      // [ks][key][32d] unpadded
    __shared__ bf16 Vt[2 * 64 * 32];      // [ks][d][32key], XOR-swizzled
    __shared__ bf16 Pl[4 * 32 * 72];      // per-wave P [qrow][key], pad 72
    const int tid = threadIdx.x;
    const int w = tid >> 6, lane = tid & 63;
    const int li = lane & 15, quad = lane >> 4;
    const int b = blockIdx.y >> 3, hd = blockIdx.y & 7;
    const int q0 = blockIdx.x * 128;
    const int qw = q0 + w * 32;                    // wave's q base
    const long rowb = (long)b * SEQ;
    const bf16* Qb = QVR + hd * DK;
    const bf16* Hb = QVR + 1024 + hd * DK;
    const bf16* Vb = QVR + 512 + hd * DK;
    bf16* Pw = &Pl[w * 32 * 72];
    const f32x4 z4 = {0.f, 0.f, 0.f, 0.f};

    // Q as A-operand fragments (verified round 3/4 mapping)
    short8 qa[2][2];
    #pragma unroll
    for (int mt = 0; mt < 2; mt++)
        #pragma unroll
        for (int ks = 0; ks < 2; ks++)
            qa[mt][ks] = *(const short8*)&Qb[(rowb + qw + mt * 16 + li) * 1536
                                             + ks * 32 + quad * 8];

    f32x4 oacc[2][4];
    float lsum[2][4];
    #pragma unroll
    for (int mt = 0; mt < 2; mt++) {
        #pragma unroll
        for (int dt = 0; dt < 4; dt++) oacc[mt][dt] = z4;
        #pragma unroll
        for (int r = 0; r < 4; r++) lsum[mt][r] = 0.f;
    }

    for (int kt = 0; kt < SEQ; kt += 64) {
        __syncthreads();
        // K/H: async16 into two unpadded panels; wave w stages rows w*16..+15
        {
            const bf16* gk = Hb + (rowb + kt + w * 16 + (lane >> 2)) * 1536
                             + (lane & 3) * 8;
            async16(&Kt[w * 512], gk);
            async16(&Kt[2048 + w * 512], gk + 32);
        }
        // V^T: VGPR staging, transpose scatter with XOR swizzle
        #pragma unroll
        for (int i = 0; i < 2; i++) {
            int item = tid + i * 256;
            int k = item >> 3, c8 = (item & 7) * 8;
            uint4 vv = *(const uint4*)&Vb[(rowb + kt + k) * 1536 + c8];
            bf16 tmp[8];
            *(uint4*)tmp = vv;
            int base = (k >> 5) * 2048;
            int colp = (k & 31) ^ (((c8 >> 3) & 3) << 3);
            #pragma unroll
            for (int j = 0; j < 8; j++) Vt[base + (c8 + j) * 32 + colp] = tmp[j];
        }
        __syncthreads();

        // ---- S = Q K^T ----
        f32x4 sa[2][4];
        #pragma unroll
        for (int mt = 0; mt < 2; mt++)
            #pragma unroll
            for (int nt = 0; nt < 4; nt++) sa[mt][nt] = z4;
        #pragma unroll
        for (int ks = 0; ks < 2; ks++) {
            short8 kb[4];
            #pragma unroll
            for (int nt = 0; nt < 4; nt++)
                kb[nt] = *(const short8*)&Kt[ks * 2048 + (nt * 16 + li) * 32 + quad * 8];
            #pragma unroll
            for (int mt = 0; mt < 2; mt++)
                #pragma unroll
                for (int nt = 0; nt < 4; nt++)
                    sa[mt][nt] = __builtin_amdgcn_mfma_f32_16x16x32_bf16(
                        qa[mt][ks], kb[nt], sa[mt][nt], 0, 0, 0);
        }

        // ---- no-max softmax; l deferred ----
        bool nomask  = (kt + 63 <= qw);        // max key <= min q
        bool allmask = (kt > qw + 31);         // min key > max q
        if (nomask || allmask) {
            float MB = allmask ? MC2 : 0.0f;
            #pragma unroll
            for (int mt = 0; mt < 2; mt++)
                #pragma unroll
                for (int nt = 0; nt < 4; nt++) {
                    f32x4 s = sa[mt][nt];
                    #pragma unroll
                    for (int r = 0; r < 4; r++) {
                        float p = exp2f(fmaf(s[r], SC2, MB));
                        lsum[mt][r] += p;
                        Pw[(mt * 16 + quad * 4 + r) * 72 + nt * 16 + li] = f2b(p);
                    }
                }
        } else {
            #pragma unroll
            for (int mt = 0; mt < 2; mt++) {
                int qrow = qw + mt * 16 + quad * 4;     // + r below
                #pragma unroll
                for (int nt = 0; nt < 4; nt++) {
                    int key = kt + nt * 16 + li;
                    f32x4 s = sa[mt][nt];
                    #pragma unroll
                    for (int r = 0; r < 4; r++) {
                        float mb = (key > qrow + r) ? MC2 : 0.0f;
                        float p = exp2f(fmaf(s[r], SC2, mb));
                        lsum[mt][r] += p;
                        Pw[(mt * 16 + quad * 4 + r) * 72 + nt * 16 + li] = f2b(p);
                    }
                }
            }
        }

        // ---- O += P V ----
        #pragma unroll
        for (int ks = 0; ks < 2; ks++) {
            short8 vbf[4], pa[2];
            #pragma unroll
            for (int dt = 0; dt < 4; dt++) {
                int d = dt * 16 + li;
                int sw = ((d >> 3) & 3) << 3;
                vbf[dt] = *(const short8*)&Vt[ks * 2048 + d * 32 + ((quad * 8) ^ sw)];
            }
            #pragma unroll
            for (int mt = 0; mt < 2; mt++)
                pa[mt] = *(const short8*)&Pw[(mt * 16 + li) * 72 + ks * 32 + quad * 8];
            #pragma unroll
            for (int mt = 0; mt < 2; mt++)
                #pragma unroll
                for (int dt = 0; dt < 4; dt++)
                    oacc[mt][dt] = __builtin_amdgcn_mfma_f32_16x16x32_bf16(
                        pa[mt], vbf[dt], oacc[mt][dt], 0, 0, 0);
        }
    }

    // final l reduction across the 16-lane key groups, then normalize+store
    #pragma unroll
    for (int mt = 0; mt < 2; mt++)
        #pragma unroll
        for (int r = 0; r < 4; r++) {
            float l = lsum[mt][r];
            l += __shfl_xor(l, 1);
            l += __shfl_xor(l, 2);
            l += __shfl_xor(l, 4);
            l += __shfl_xor(l, 8);
            float inv = 1.0f / l;
            long row = rowb + qw + mt * 16 + quad * 4 + r;
            #pragma unroll
            for (int dt = 0; dt < 4; dt++)
                O[row * 512 + hd * 64 + dt * 16 + li] = f2b(oacc[mt][dt][r] * inv);
        }
}

// ---------------------------------------------------------------------------
// LN1: xb + AO (both bf16 plain) -> X1 bf16 plain
// ---------------------------------------------------------------------------
__global__ __launch_bounds__(256) void ln1_kernel(const bf16* __restrict__ xb,
                                                  const bf16* __restrict__ ao,
                                                  const void* __restrict__ g,
                                                  const void* __restrict__ beta,
                                                  bf16* __restrict__ x1,
                                                  const int* __restrict__ flagp)
{
    const int f32 = *flagp;
    long base = (long)blockIdx.x * 512;
    int tid = threadIdx.x;
    float v[2];
    #pragma unroll
    for (int i = 0; i < 2; i++) {
        int d = tid + i * 256;
        v[i] = b2f(xb[base + d]) + b2f(ao[base + d]);
    }
    float s1 = v[0] + v[1];
    float s2 = v[0] * v[0] + v[1] * v[1];
    #pragma unroll
    for (int off = 32; off > 0; off >>= 1) {
        s1 += __shfl_down(s1, off);
        s2 += __shfl_down(s2, off);
    }
    __shared__ float w1[4], w2[4];
    int wid = tid >> 6, lane = tid & 63;
    if (lane == 0) { w1[wid] = s1; w2[wid] = s2; }
    __syncthreads();
    float t1 = w1[0] + w1[1] + w1[2] + w1[3];
    float t2 = w2[0] + w2[1] + w2[2] + w2[3];
    float mu = t1 * (1.0f / DMODEL);
    float var = t2 * (1.0f / DMODEL) - mu * mu;
    float rs = rsqrtf(var + 1e-5f);
    #pragma unroll
    for (int i = 0; i < 2; i++) {
        int d = tid + i * 256;
        x1[base + d] = f2b((v[i] - mu) * rs * ldE(g, d, f32) + ldE(beta, d, f32));
    }
}

// ---------------------------------------------------------------------------
// LN2: X1 + FF2 -> d_out (external dtype, (S,B,D) layout)
// ---------------------------------------------------------------------------
__global__ __launch_bounds__(256) void ln2_kernel(const bf16* __restrict__ x1,
                                                  const bf16* __restrict__ ff2,
                                                  const void* __restrict__ g,
                                                  const void* __restrict__ beta,
                                                  void* __restrict__ outp,
                                                  const int* __restrict__ flagp)
{
    const int f32 = *flagp;
    int m = blockIdx.x;                 // b*SEQ + s
    int b = m >> 11, s = m & 2047;
    long plain = (long)m * 512;
    long funny = ((long)s * BATCH + b) * 512;
    int tid = threadIdx.x;
    float v[2];
    #pragma unroll
    for (int i = 0; i < 2; i++) {
        int d = tid + i * 256;
        v[i] = b2f(x1[plain + d]) + b2f(ff2[plain + d]);
    }
    float s1 = v[0] + v[1];
    float s2 = v[0] * v[0] + v[1] * v[1];
    #pragma unroll
    for (int off = 32; off > 0; off >>= 1) {
        s1 += __shfl_down(s1, off);
        s2 += __shfl_down(s2, off);
    }
    __shared__ float w1[4], w2[4];
    int wid = tid >> 6, lane = tid & 63;
    if (lane == 0) { w1[wid] = s1; w2[wid] = s2; }
    __syncthreads();
    float t1 = w1[0] + w1[1] + w1[2] + w1[3];
    float t2 = w2[0] + w2[1] + w2[2] + w2[3];
    float mu = t1 * (1.0f / DMODEL);
    float var = t2 * (1.0f / DMODEL) - mu * mu;
    float rs = rsqrtf(var + 1e-5f);
    #pragma unroll
    for (int i = 0; i < 2; i++) {
        int d = tid + i * 256;
        float r = (v[i] - mu) * rs * ldE(g, d, f32) + ldE(beta, d, f32);
        if (f32) ((float*)outp)[funny + d] = r;
        else     ((bf16*)outp)[funny + d] = f2b(r);
    }
}

// ---------------------------------------------------------------------------
extern "C" void kernel_launch(void* const* d_in, const int* in_sizes, int n_in,
                              void* d_out, int out_size, void* d_ws, size_t ws_size,
                              hipStream_t stream)
{
    (void)in_sizes; (void)n_in; (void)out_size; (void)ws_size;
    const void* x = d_in[0];

    // bf16 workspace layout (elements):
    bf16* W    = (bf16*)d_ws;
    bf16* xb   = W;                       // [0, 8M)   dead after LN1
    bf16* QVR  = W + (8u  << 20);         // [8M, 32M) Q|V|R cols, dead after attn
    bf16* Ob   = W + (32u << 20);         // [32M,40M) dead after Wo gemm
    bf16* AO   = W + (40u << 20);         // [40M,48M) dead after LN1
    bf16* X1   = W + (8u  << 20);         // reuse QVR head, alive until LN2
    bf16* FFH  = W + (16u << 20);         // [16M,48M) after LN1
    bf16* FF2  = W;                       // reuse xb
    int*  flag = (int*)((char*)d_ws + (size_t)96 * 1024 * 1024);
    bf16* Wt   = (bf16*)((char*)d_ws + (size_t)96 * 1024 * 1024 + 16);
    bf16* Wqvr = Wt;                      // [1536][512]
    bf16* Wob  = Wt + 786432;             // [512][512]
    bf16* Wf1t = Wt + 1048576;            // [2048][512]
    bf16* Wf2t = Wt + 2097152;            // [512][2048]
    bf16* bqvr = Wt + 3145728;
    bf16* bob  = Wt + 3147264;
    bf16* bf1b = Wt + 3147776;
    bf16* bf2b = Wt + 3149824;

    dim3 blk(256);
    probe_kernel<<<1, blk, 0, stream>>>(x, flag);
    convert_x<<<4096, blk, 0, stream>>>(x, xb, flag);
    prep_weights<<<12306, blk, 0, stream>>>(
        d_in[1], d_in[3], d_in[5], d_in[8], d_in[12], d_in[14],
        d_in[2], d_in[4], d_in[6], d_in[9], d_in[13], d_in[15],
        Wqvr, Wob, Wf1t, Wf2t, bqvr, bob, bf1b, bf2b, flag);

    // fused Q|V|R projection: [16384,512] x [1536,512]^T -> QVR (ldc 1536)
    mfma_gemm<false><<<dim3(128, 12), blk, 0, stream>>>(xb, Wqvr, bqvr, QVR, 512, 512, 1536);

    // recurrence in place on R slice
    recur_kernel<<<16, blk, 0, stream>>>(QVR, d_in[7], flag);

    // attention
    attn_mfma<<<dim3(16, 64), blk, 0, stream>>>(QVR, Ob);

    // Wo projection
    mfma_gemm<false><<<dim3(128, 4), blk, 0, stream>>>(Ob, Wob, bob, AO, 512, 512, 512);

    // LN1
    ln1_kernel<<<MROWS, blk, 0, stream>>>(xb, AO, d_in[10], d_in[11], X1, flag);

    // FF1 (relu)
    mfma_gemm<true><<<dim3(128, 16), blk, 0, stream>>>(X1, Wf1t, bf1b, FFH, 512, 512, 2048);

    // FF2
    mfma_gemm<false><<<dim3(128, 4), blk, 0, stream>>>(FFH, Wf2t, bf2b, FF2, 2048, 2048, 512);

    // LN2 -> d_out
    ln2_kernel<<<MROWS, blk, 0, stream>>>(X1, FF2, d_in[16], d_in[17], d_out, flag);
}

// Round 6
// 576.561 us; speedup vs baseline: 7.7266x; 1.0937x over previous
//
#include <hip/hip_runtime.h>
#include <hip/hip_bf16.h>
#include <math.h>

#define SEQ    2048
#define BATCH  8
#define DMODEL 512
#define NHEADS 8
#define DK     64
#define DFF    2048
#define MROWS  16384

typedef __hip_bfloat16 bf16;
typedef unsigned int   u32;
typedef unsigned short u16;
typedef __attribute__((ext_vector_type(8))) short short8;   // 8 bf16 = 4 VGPR
typedef __attribute__((ext_vector_type(4))) float f32x4;

#define LOG2E  1.4426950408889634f
#define LOG2E2 2.8853900817779268f   // 2*log2(e)
#define MC2    1.4426950408889634f   // log2(e) : +1.0-mask in exp2 domain

__device__ __forceinline__ float b2f(bf16 v) { return __bfloat162float(v); }
__device__ __forceinline__ bf16  f2b(float f) { return __float2bfloat16(f); }
__device__ __forceinline__ u16 f2u(float f) { bf16 h = __float2bfloat16(f); return *(u16*)&h; }
__device__ __forceinline__ u32 pack2(float a, float b) {
    return ((u32)f2u(b) << 16) | (u32)f2u(a);
}
// external-tensor load: dtype decided at runtime by probe flag (0=bf16, 1=fp32)
__device__ __forceinline__ float ldE(const void* p, long off, int f32) {
    return f32 ? ((const float*)p)[off] : b2f(((const bf16*)p)[off]);
}
// async global->LDS, 16B per lane; lds base must be wave-uniform
__device__ __forceinline__ void async16(bf16* lds, const bf16* g) {
    __builtin_amdgcn_global_load_lds(
        (const __attribute__((address_space(1))) void*)g,
        (__attribute__((address_space(3))) void*)lds, 16, 0, 0);
}

// ---------------------------------------------------------------------------
// Dtype probe (verified round 2): flag=1 means fp32 inputs.
// ---------------------------------------------------------------------------
__global__ __launch_bounds__(256) void probe_kernel(const void* __restrict__ x,
                                                    int* __restrict__ flag)
{
    int tid = threadIdx.x;
    const u16* u = (const u16*)x;
    int cnt = 0;
    #pragma unroll
    for (int i = 0; i < 8; i++) {
        u16 e = u[tid * 8 + i];
        float v = __uint_as_float(((u32)e) << 16);
        float a = fabsf(v);
        if (a > 9.313226e-10f && a < 1.0737418e9f) cnt++;
    }
    __shared__ int sh[256];
    sh[tid] = cnt;
    __syncthreads();
    for (int s = 128; s > 0; s >>= 1) {
        if (tid < s) sh[tid] += sh[tid + s];
        __syncthreads();
    }
    if (tid == 0) *flag = (sh[0] < 1700) ? 1 : 0;
}

// ---------------------------------------------------------------------------
// Merged prep: blocks 0..4095 convert x (S,B,D) -> xb bf16 [b*SEQ+s][512];
// blocks 4096.. pack weights to bf16 [N][K].  Wq,bq pre-scaled by log2e
// (softmax scale folded into Q so attention exp2 needs no fma).
// ---------------------------------------------------------------------------
__global__ __launch_bounds__(256) void prep_all(
    const void* x, bf16* __restrict__ xb,
    const void* Wq, const void* Wv, const void* Wr, const void* Wo,
    const void* Wf1, const void* Wf2,
    const void* bq, const void* bv, const void* br, const void* bo,
    const void* bf1, const void* bf2,
    bf16* __restrict__ Wqvr, bf16* __restrict__ Wob,
    bf16* __restrict__ Wf1t, bf16* __restrict__ Wf2t,
    bf16* __restrict__ bqvr, bf16* __restrict__ bob,
    bf16* __restrict__ bf1b, bf16* __restrict__ bf2b,
    const int* __restrict__ flagp)
{
    const int f32 = *flagp;
    int bid = blockIdx.x;
    if (bid < 4096) {
        int gid = bid * 256 + threadIdx.x;             // 0..1048575
        int row_in = gid >> 6;                         // s*8+b
        int d8 = (gid & 63) * 8;
        int s = row_in >> 3, b = row_in & 7;
        long src = (long)row_in * 512 + d8;
        long dst = ((long)b * SEQ + s) * 512 + d8;
        if (f32) {
            const float* xf = (const float*)x;
            float4 a = *(const float4*)(xf + src);
            float4 c = *(const float4*)(xf + src + 4);
            u32 o[4] = { pack2(a.x,a.y), pack2(a.z,a.w), pack2(c.x,c.y), pack2(c.z,c.w) };
            *(uint4*)(xb + dst) = *(uint4*)o;
        } else {
            *(uint4*)(xb + dst) = *(const uint4*)((const bf16*)x + src);
        }
        return;
    }
    long g = (long)(bid - 4096) * 256 + threadIdx.x;   // < 3150336
    if (g < 786432) {
        if (g < 262144) Wqvr[g] = f2b(ldE(Wq, g, f32) * LOG2E);   // Q scaled
        else if (g < 524288) Wqvr[g] = f2b(ldE(Wv, g & 262143, f32));
        else Wqvr[g] = f2b(ldE(Wr, g & 262143, f32));
    } else if (g < 1048576) {
        long j = g - 786432;
        Wob[j] = f2b(ldE(Wo, j, f32));
    } else if (g < 2097152) {
        long j = g - 1048576;
        long n = j >> 9, k = j & 511;
        Wf1t[j] = f2b(ldE(Wf1, k * 2048 + n, f32));
    } else if (g < 3145728) {
        long j = g - 2097152;
        long n = j >> 11, k = j & 2047;
        Wf2t[j] = f2b(ldE(Wf2, k * 512 + n, f32));
    } else {
        long j = g - 3145728;
        if (j < 512)       bqvr[j]      = f2b(ldE(bq, j, f32) * LOG2E);
        else if (j < 1024) bqvr[j]      = f2b(ldE(bv, j - 512, f32));
        else if (j < 1536) bqvr[j]      = f2b(ldE(br, j - 1024, f32));
        else if (j < 2048) bob[j-1536]  = f2b(ldE(bo, j - 1536, f32));
        else if (j < 4096) bf1b[j-2048] = f2b(ldE(bf1, j - 2048, f32));
        else if (j < 4608) bf2b[j-4096] = f2b(ldE(bf2, j - 4096, f32));
    }
}

// ---------------------------------------------------------------------------
// MFMA GEMM body (m97 structure): C[m][n] = sum_k A[m][k]*W[n][k] + bias[n]
// ---------------------------------------------------------------------------
template<bool RELU>
__device__ __forceinline__ void gemm_body(
    const bf16* __restrict__ A, const bf16* __restrict__ W,
    const bf16* __restrict__ bias, bf16* __restrict__ C,
    int K, int lda, int ldc, int bx, int by, bf16* As, bf16* Bs)
{
    const int tid = threadIdx.x;
    const int w = tid >> 6, lane = tid & 63;
    const int li = lane & 15, quad = lane >> 4;
    const int m0 = bx * 128, n0 = by * 128;
    const int wm = (w >> 1) * 64, wn = (w & 1) * 64;
    const int srow = lane >> 2, scol = (lane & 3) * 8;

    f32x4 acc[4][4];
    const f32x4 z4 = {0.f, 0.f, 0.f, 0.f};
    #pragma unroll
    for (int i = 0; i < 4; i++)
        #pragma unroll
        for (int j = 0; j < 4; j++) acc[i][j] = z4;

    const bf16* ga = A + (long)(m0 + w * 32 + srow) * lda + scol;
    const bf16* gb = W + (long)(n0 + w * 32 + srow) * K + scol;
    bf16* lA0 = &As[(w * 32) * 32];
    bf16* lA1 = &As[(w * 32 + 16) * 32];
    bf16* lB0 = &Bs[(w * 32) * 32];
    bf16* lB1 = &Bs[(w * 32 + 16) * 32];

    for (int k0 = 0; k0 < K; k0 += 32) {
        __syncthreads();
        async16(lA0, ga);
        async16(lA1, ga + (long)16 * lda);
        async16(lB0, gb);
        async16(lB1, gb + (long)16 * K);
        ga += 32; gb += 32;
        __syncthreads();
        short8 af[4], bfr[4];
        #pragma unroll
        for (int t = 0; t < 4; t++)
            af[t] = *(const short8*)&As[(wm + t * 16 + li) * 32 + quad * 8];
        #pragma unroll
        for (int t = 0; t < 4; t++)
            bfr[t] = *(const short8*)&Bs[(wn + t * 16 + li) * 32 + quad * 8];
        #pragma unroll
        for (int i = 0; i < 4; i++)
            #pragma unroll
            for (int j = 0; j < 4; j++)
                acc[i][j] = __builtin_amdgcn_mfma_f32_16x16x32_bf16(
                    af[i], bfr[j], acc[i][j], 0, 0, 0);
    }

    #pragma unroll
    for (int i = 0; i < 4; i++) {
        #pragma unroll
        for (int j = 0; j < 4; j++) {
            int col = n0 + wn + j * 16 + li;
            float bb = b2f(bias[col]);
            #pragma unroll
            for (int r = 0; r < 4; r++) {
                int row = m0 + wm + i * 16 + quad * 4 + r;
                float v = acc[i][j][r] + bb;
                if (RELU) v = fmaxf(v, 0.f);
                C[(long)row * ldc + col] = f2b(v);
            }
        }
    }
}

template<bool RELU>
__global__ __launch_bounds__(256) void mfma_gemm(
    const bf16* __restrict__ A, const bf16* __restrict__ W,
    const bf16* __restrict__ bias, bf16* __restrict__ C,
    int K, int lda, int ldc)
{
    __shared__ bf16 As[128 * 32];
    __shared__ bf16 Bs[128 * 32];
    gemm_body<RELU>(A, W, bias, C, K, lda, ldc, blockIdx.x, blockIdx.y, As, Bs);
}

// ---------------------------------------------------------------------------
// Recurrence body (verified round 4) on R slice of QVR. Stores h*0.125
// (exact pow-2 prescale for attention exp2); true h carried in-register.
// ---------------------------------------------------------------------------
__device__ __forceinline__ void recur_body(bf16* __restrict__ QVR,
                                           const void* __restrict__ Wh,
                                           int f32, int idx)
{
    int b = idx >> 9, o = idx & 511;
    float w = 0.0f;
    #pragma unroll
    for (int k = 0; k < DK; k++) w += ldE(Wh, (long)o * DK + k, f32);
    const float w2 = w * LOG2E2;
    bf16* base = QVR + (long)b * SEQ * 1536 + 1024 + o;

    const int PF = 32;
    float buf[PF];
    #pragma unroll
    for (int i = 0; i < PF; i++)
        buf[i] = b2f(base[(long)i * 1536]) * LOG2E2;

    float h = 0.0f;
    for (int s = 0; s < SEQ; s += PF) {
        float nbuf[PF];
        if (s + PF < SEQ) {
            #pragma unroll
            for (int i = 0; i < PF; i++)
                nbuf[i] = b2f(base[(long)(s + PF + i) * 1536]) * LOG2E2;
        }
        #pragma unroll
        for (int i = 0; i < PF; i++) {
            float xx = fmaf(h, w2, buf[i]);            // 2*log2e*(h*w + r)
            float e  = __builtin_amdgcn_exp2f(xx);
            float d  = __builtin_amdgcn_rcpf(e + 1.0f);
            h = fmaf(-2.0f, d, 1.0f);                  // tanh
            base[(long)(s + i) * 1536] = f2b(h * 0.125f);  // store pre-scaled
        }
        #pragma unroll
        for (int i = 0; i < PF; i++) buf[i] = nbuf[i];
    }
}

// ---------------------------------------------------------------------------
// Fused: blocks 0..15 run the recurrence (R slice, cols 1024+) while blocks
// 16..1039 run the Q|V projection (cols 0..1023). Disjoint writes; the R
// projection completed in the previous launch -> order-independent (G16).
// ---------------------------------------------------------------------------
__global__ __launch_bounds__(256) void fused_qv_recur(
    const bf16* __restrict__ xb, const bf16* __restrict__ Wqvr,
    const bf16* __restrict__ bqvr, bf16* __restrict__ QVR,
    const void* __restrict__ Wh, const int* __restrict__ flagp)
{
    __shared__ bf16 As[128 * 32];
    __shared__ bf16 Bs[128 * 32];
    if (blockIdx.x < 16) {
        recur_body(QVR, Wh, *flagp, blockIdx.x * 256 + threadIdx.x);
    } else {
        int bx = blockIdx.x - 16;
        gemm_body<false>(xb, Wqvr, bqvr, QVR, 512, 512, 1536,
                         bx & 127, bx >> 7, As, Bs);
    }
}

// ---------------------------------------------------------------------------
// MFMA flash attention, round-6: Q pre-scaled by log2e (weights), H by 1/8
// (recurrence store) -> p = v_exp_f32(s) with no fma on no-mask tiles.
// l computed by MFMA against a ones B-fragment (row-sum on the matrix pipe),
// removing per-lane adds + the final shfl tree. Rest as round 5 (verified).
// ---------------------------------------------------------------------------
__global__ __launch_bounds__(256) void attn_mfma(const bf16* __restrict__ QVR,
                                                 bf16* __restrict__ O)
{
    __shared__ bf16 Kt[2 * 64 * 32];      // [ks][key][32d] unpadded
    __shared__ bf16 Vt[2 * 64 * 32];      // [ks][d][32key], XOR-swizzled
    __shared__ bf16 Pl[4 * 32 * 72];      // per-wave P [qrow][key], pad 72
    const int tid = threadIdx.x;
    const int w = tid >> 6, lane = tid & 63;
    const int li = lane & 15, quad = lane >> 4;
    const int b = blockIdx.y >> 3, hd = blockIdx.y & 7;
    const int q0 = blockIdx.x * 128;
    const int qw = q0 + w * 32;                    // wave's q base
    const long rowb = (long)b * SEQ;
    const bf16* Qb = QVR + hd * DK;
    const bf16* Hb = QVR + 1024 + hd * DK;
    const bf16* Vb = QVR + 512 + hd * DK;
    bf16* Pw = &Pl[w * 32 * 72];
    const f32x4 z4 = {0.f, 0.f, 0.f, 0.f};

    short8 ones;
    #pragma unroll
    for (int i = 0; i < 8; i++) ones[i] = (short)0x3F80;   // bf16 1.0

    // Q as A-operand fragments (verified round 3/4 mapping)
    short8 qa[2][2];
    #pragma unroll
    for (int mt = 0; mt < 2; mt++)
        #pragma unroll
        for (int ks = 0; ks < 2; ks++)
            qa[mt][ks] = *(const short8*)&Qb[(rowb + qw + mt * 16 + li) * 1536
                                             + ks * 32 + quad * 8];

    f32x4 oacc[2][4];
    f32x4 lacc[2];
    #pragma unroll
    for (int mt = 0; mt < 2; mt++) {
        #pragma unroll
        for (int dt = 0; dt < 4; dt++) oacc[mt][dt] = z4;
        lacc[mt] = z4;
    }

    for (int kt = 0; kt < SEQ; kt += 64) {
        __syncthreads();
        // K/H: async16 into two unpadded panels; wave w stages rows w*16..+15
        {
            const bf16* gk = Hb + (rowb + kt + w * 16 + (lane >> 2)) * 1536
                             + (lane & 3) * 8;
            async16(&Kt[w * 512], gk);
            async16(&Kt[2048 + w * 512], gk + 32);
        }
        // V^T: VGPR staging, transpose scatter with XOR swizzle
        #pragma unroll
        for (int i = 0; i < 2; i++) {
            int item = tid + i * 256;
            int k = item >> 3, c8 = (item & 7) * 8;
            uint4 vv = *(const uint4*)&Vb[(rowb + kt + k) * 1536 + c8];
            bf16 tmp[8];
            *(uint4*)tmp = vv;
            int base = (k >> 5) * 2048;
            int colp = (k & 31) ^ (((c8 >> 3) & 3) << 3);
            #pragma unroll
            for (int j = 0; j < 8; j++) Vt[base + (c8 + j) * 32 + colp] = tmp[j];
        }
        __syncthreads();

        // ---- S = Q K^T  (already exp2-domain: Q *= log2e, H *= 1/8) ----
        f32x4 sa[2][4];
        #pragma unroll
        for (int mt = 0; mt < 2; mt++)
            #pragma unroll
            for (int nt = 0; nt < 4; nt++) sa[mt][nt] = z4;
        #pragma unroll
        for (int ks = 0; ks < 2; ks++) {
            short8 kb[4];
            #pragma unroll
            for (int nt = 0; nt < 4; nt++)
                kb[nt] = *(const short8*)&Kt[ks * 2048 + (nt * 16 + li) * 32 + quad * 8];
            #pragma unroll
            for (int mt = 0; mt < 2; mt++)
                #pragma unroll
                for (int nt = 0; nt < 4; nt++)
                    sa[mt][nt] = __builtin_amdgcn_mfma_f32_16x16x32_bf16(
                        qa[mt][ks], kb[nt], sa[mt][nt], 0, 0, 0);
        }

        // ---- p = exp2(s [+ log2e]); write P; l deferred to MFMA ----
        bool nomask  = (kt + 63 <= qw);        // max key <= min q
        bool allmask = (kt > qw + 31);         // min key > max q
        if (nomask || allmask) {
            float MB = allmask ? MC2 : 0.0f;
            #pragma unroll
            for (int mt = 0; mt < 2; mt++)
                #pragma unroll
                for (int nt = 0; nt < 4; nt++) {
                    f32x4 s = sa[mt][nt];
                    #pragma unroll
                    for (int r = 0; r < 4; r++) {
                        float p = __builtin_amdgcn_exp2f(s[r] + MB);
                        Pw[(mt * 16 + quad * 4 + r) * 72 + nt * 16 + li] = f2b(p);
                    }
                }
        } else {
            #pragma unroll
            for (int mt = 0; mt < 2; mt++) {
                int qrow = qw + mt * 16 + quad * 4;     // + r below
                #pragma unroll
                for (int nt = 0; nt < 4; nt++) {
                    int key = kt + nt * 16 + li;
                    f32x4 s = sa[mt][nt];
                    #pragma unroll
                    for (int r = 0; r < 4; r++) {
                        float arg = (key > qrow + r) ? s[r] + MC2 : s[r];
                        float p = __builtin_amdgcn_exp2f(arg);
                        Pw[(mt * 16 + quad * 4 + r) * 72 + nt * 16 + li] = f2b(p);
                    }
                }
            }
        }

        // ---- O += P V ;  l += P 1 (matrix pipe) ----
        #pragma unroll
        for (int ks = 0; ks < 2; ks++) {
            short8 vbf[4], pa[2];
            #pragma unroll
            for (int dt = 0; dt < 4; dt++) {
                int d = dt * 16 + li;
                int sw = ((d >> 3) & 3) << 3;
                vbf[dt] = *(const short8*)&Vt[ks * 2048 + d * 32 + ((quad * 8) ^ sw)];
            }
            #pragma unroll
            for (int mt = 0; mt < 2; mt++)
                pa[mt] = *(const short8*)&Pw[(mt * 16 + li) * 72 + ks * 32 + quad * 8];
            #pragma unroll
            for (int mt = 0; mt < 2; mt++) {
                lacc[mt] = __builtin_amdgcn_mfma_f32_16x16x32_bf16(
                    pa[mt], ones, lacc[mt], 0, 0, 0);
                #pragma unroll
                for (int dt = 0; dt < 4; dt++)
                    oacc[mt][dt] = __builtin_amdgcn_mfma_f32_16x16x32_bf16(
                        pa[mt], vbf[dt], oacc[mt][dt], 0, 0, 0);
            }
        }
    }

    // l is already the full row-sum in every lane (all columns identical)
    #pragma unroll
    for (int mt = 0; mt < 2; mt++)
        #pragma unroll
        for (int r = 0; r < 4; r++) {
            float inv = 1.0f / lacc[mt][r];
            long row = rowb + qw + mt * 16 + quad * 4 + r;
            #pragma unroll
            for (int dt = 0; dt < 4; dt++)
                O[row * 512 + hd * 64 + dt * 16 + li] = f2b(oacc[mt][dt][r] * inv);
        }
}

// ---------------------------------------------------------------------------
// LN1: xb + AO (both bf16 plain) -> X1 bf16 plain
// ---------------------------------------------------------------------------
__global__ __launch_bounds__(256) void ln1_kernel(const bf16* __restrict__ xb,
                                                  const bf16* __restrict__ ao,
                                                  const void* __restrict__ g,
                                                  const void* __restrict__ beta,
                                                  bf16* __restrict__ x1,
                                                  const int* __restrict__ flagp)
{
    const int f32 = *flagp;
    long base = (long)blockIdx.x * 512;
    int tid = threadIdx.x;
    float v[2];
    #pragma unroll
    for (int i = 0; i < 2; i++) {
        int d = tid + i * 256;
        v[i] = b2f(xb[base + d]) + b2f(ao[base + d]);
    }
    float s1 = v[0] + v[1];
    float s2 = v[0] * v[0] + v[1] * v[1];
    #pragma unroll
    for (int off = 32; off > 0; off >>= 1) {
        s1 += __shfl_down(s1, off);
        s2 += __shfl_down(s2, off);
    }
    __shared__ float w1[4], w2[4];
    int wid = tid >> 6, lane = tid & 63;
    if (lane == 0) { w1[wid] = s1; w2[wid] = s2; }
    __syncthreads();
    float t1 = w1[0] + w1[1] + w1[2] + w1[3];
    float t2 = w2[0] + w2[1] + w2[2] + w2[3];
    float mu = t1 * (1.0f / DMODEL);
    float var = t2 * (1.0f / DMODEL) - mu * mu;
    float rs = rsqrtf(var + 1e-5f);
    #pragma unroll
    for (int i = 0; i < 2; i++) {
        int d = tid + i * 256;
        x1[base + d] = f2b((v[i] - mu) * rs * ldE(g, d, f32) + ldE(beta, d, f32));
    }
}

// ---------------------------------------------------------------------------
// LN2: X1 + FF2 -> d_out (external dtype, (S,B,D) layout)
// ---------------------------------------------------------------------------
__global__ __launch_bounds__(256) void ln2_kernel(const bf16* __restrict__ x1,
                                                  const bf16* __restrict__ ff2,
                                                  const void* __restrict__ g,
                                                  const void* __restrict__ beta,
                                                  void* __restrict__ outp,
                                                  const int* __restrict__ flagp)
{
    const int f32 = *flagp;
    int m = blockIdx.x;                 // b*SEQ + s
    int b = m >> 11, s = m & 2047;
    long plain = (long)m * 512;
    long funny = ((long)s * BATCH + b) * 512;
    int tid = threadIdx.x;
    float v[2];
    #pragma unroll
    for (int i = 0; i < 2; i++) {
        int d = tid + i * 256;
        v[i] = b2f(x1[plain + d]) + b2f(ff2[plain + d]);
    }
    float s1 = v[0] + v[1];
    float s2 = v[0] * v[0] + v[1] * v[1];
    #pragma unroll
    for (int off = 32; off > 0; off >>= 1) {
        s1 += __shfl_down(s1, off);
        s2 += __shfl_down(s2, off);
    }
    __shared__ float w1[4], w2[4];
    int wid = tid >> 6, lane = tid & 63;
    if (lane == 0) { w1[wid] = s1; w2[wid] = s2; }
    __syncthreads();
    float t1 = w1[0] + w1[1] + w1[2] + w1[3];
    float t2 = w2[0] + w2[1] + w2[2] + w2[3];
    float mu = t1 * (1.0f / DMODEL);
    float var = t2 * (1.0f / DMODEL) - mu * mu;
    float rs = rsqrtf(var + 1e-5f);
    #pragma unroll
    for (int i = 0; i < 2; i++) {
        int d = tid + i * 256;
        float r = (v[i] - mu) * rs * ldE(g, d, f32) + ldE(beta, d, f32);
        if (f32) ((float*)outp)[funny + d] = r;
        else     ((bf16*)outp)[funny + d] = f2b(r);
    }
}

// ---------------------------------------------------------------------------
extern "C" void kernel_launch(void* const* d_in, const int* in_sizes, int n_in,
                              void* d_out, int out_size, void* d_ws, size_t ws_size,
                              hipStream_t stream)
{
    (void)in_sizes; (void)n_in; (void)out_size; (void)ws_size;
    const void* x = d_in[0];

    // bf16 workspace layout (elements):
    bf16* W    = (bf16*)d_ws;
    bf16* xb   = W;                       // [0, 8M)   dead after LN1
    bf16* QVR  = W + (8u  << 20);         // [8M, 32M) Q|V|R cols, dead after attn
    bf16* Ob   = W + (32u << 20);         // [32M,40M) dead after Wo gemm
    bf16* AO   = W + (40u << 20);         // [40M,48M) dead after LN1
    bf16* X1   = W + (8u  << 20);         // reuse QVR head, alive until LN2
    bf16* FFH  = W + (16u << 20);         // [16M,48M) after LN1
    bf16* FF2  = W;                       // reuse xb
    int*  flag = (int*)((char*)d_ws + (size_t)96 * 1024 * 1024);
    bf16* Wt   = (bf16*)((char*)d_ws + (size_t)96 * 1024 * 1024 + 16);
    bf16* Wqvr = Wt;                      // [1536][512]
    bf16* Wob  = Wt + 786432;             // [512][512]
    bf16* Wf1t = Wt + 1048576;            // [2048][512]
    bf16* Wf2t = Wt + 2097152;            // [512][2048]
    bf16* bqvr = Wt + 3145728;
    bf16* bob  = Wt + 3147264;
    bf16* bf1b = Wt + 3147776;
    bf16* bf2b = Wt + 3149824;

    dim3 blk(256);
    probe_kernel<<<1, blk, 0, stream>>>(x, flag);
    prep_all<<<16402, blk, 0, stream>>>(
        x, xb,
        d_in[1], d_in[3], d_in[5], d_in[8], d_in[12], d_in[14],
        d_in[2], d_in[4], d_in[6], d_in[9], d_in[13], d_in[15],
        Wqvr, Wob, Wf1t, Wf2t, bqvr, bob, bf1b, bf2b, flag);

    // R projection only: cols 1024..1535 of QVR
    mfma_gemm<false><<<dim3(128, 4), blk, 0, stream>>>(
        xb, Wqvr + 1024 * 512, bqvr + 1024, QVR + 1024, 512, 512, 1536);

    // fused: recurrence (blocks 0..15) + Q|V projection (blocks 16..1039)
    fused_qv_recur<<<1040, blk, 0, stream>>>(xb, Wqvr, bqvr, QVR, d_in[7], flag);

    // attention
    attn_mfma<<<dim3(16, 64), blk, 0, stream>>>(QVR, Ob);

    // Wo projection
    mfma_gemm<false><<<dim3(128, 4), blk, 0, stream>>>(Ob, Wob, bob, AO, 512, 512, 512);

    // LN1
    ln1_kernel<<<MROWS, blk, 0, stream>>>(xb, AO, d_in[10], d_in[11], X1, flag);

    // FF1 (relu)
    mfma_gemm<true><<<dim3(128, 16), blk, 0, stream>>>(X1, Wf1t, bf1b, FFH, 512, 512, 2048);

    // FF2
    mfma_gemm<false><<<dim3(128, 4), blk, 0, stream>>>(FFH, Wf2t, bf2b, FF2, 2048, 2048, 512);

    // LN2 -> d_out
    ln2_kernel<<<MROWS, blk, 0, stream>>>(X1, FF2, d_in[16], d_in[17], d_out, flag);
}

// Round 7
// 540.911 us; speedup vs baseline: 8.2358x; 1.0659x over previous
//
#include <hip/hip_runtime.h>
#include <hip/hip_bf16.h>
#include <math.h>

#define SEQ    2048
#define BATCH  8
#define DMODEL 512
#define NHEADS 8
#define DK     64
#define DFF    2048
#define MROWS  16384

typedef __hip_bfloat16 bf16;
typedef unsigned int   u32;
typedef unsigned short u16;
typedef __attribute__((ext_vector_type(8))) short short8;   // 8 bf16 = 4 VGPR
typedef __attribute__((ext_vector_type(4))) float f32x4;

#define LOG2E  1.4426950408889634f
#define LOG2E2 2.8853900817779268f   // 2*log2(e)
#define MC2    1.4426950408889634f   // log2(e) : +1.0-mask in exp2 domain

__device__ __forceinline__ float b2f(bf16 v) { return __bfloat162float(v); }
__device__ __forceinline__ bf16  f2b(float f) { return __float2bfloat16(f); }
__device__ __forceinline__ u16 f2u(float f) { bf16 h = __float2bfloat16(f); return *(u16*)&h; }
__device__ __forceinline__ u32 pack2(float a, float b) {
    return ((u32)f2u(b) << 16) | (u32)f2u(a);
}
__device__ __forceinline__ void unpack2(u32 u, float& a, float& b) {
    a = __uint_as_float(u << 16);
    b = __uint_as_float(u & 0xFFFF0000u);
}
// external-tensor load: dtype decided at runtime by probe flag (0=bf16, 1=fp32)
__device__ __forceinline__ float ldE(const void* p, long off, int f32) {
    return f32 ? ((const float*)p)[off] : b2f(((const bf16*)p)[off]);
}
// async global->LDS, 16B per lane; lds base must be wave-uniform
__device__ __forceinline__ void async16(bf16* lds, const bf16* g) {
    __builtin_amdgcn_global_load_lds(
        (const __attribute__((address_space(1))) void*)g,
        (__attribute__((address_space(3))) void*)lds, 16, 0, 0);
}

// ---------------------------------------------------------------------------
// Dtype probe (verified round 2): flag=1 means fp32 inputs.
// ---------------------------------------------------------------------------
__global__ __launch_bounds__(256) void probe_kernel(const void* __restrict__ x,
                                                    int* __restrict__ flag)
{
    int tid = threadIdx.x;
    const u16* u = (const u16*)x;
    int cnt = 0;
    #pragma unroll
    for (int i = 0; i < 8; i++) {
        u16 e = u[tid * 8 + i];
        float v = __uint_as_float(((u32)e) << 16);
        float a = fabsf(v);
        if (a > 9.313226e-10f && a < 1.0737418e9f) cnt++;
    }
    __shared__ int sh[256];
    sh[tid] = cnt;
    __syncthreads();
    for (int s = 128; s > 0; s >>= 1) {
        if (tid < s) sh[tid] += sh[tid + s];
        __syncthreads();
    }
    if (tid == 0) *flag = (sh[0] < 1700) ? 1 : 0;
}

// ---------------------------------------------------------------------------
// Merged prep: blocks 0..4095 convert x; blocks 4096.. pack weights.
// Wq,bq pre-scaled by log2e (softmax scale folded into Q).
// ---------------------------------------------------------------------------
__global__ __launch_bounds__(256) void prep_all(
    const void* x, bf16* __restrict__ xb,
    const void* Wq, const void* Wv, const void* Wr, const void* Wo,
    const void* Wf1, const void* Wf2,
    const void* bq, const void* bv, const void* br, const void* bo,
    const void* bf1, const void* bf2,
    bf16* __restrict__ Wqvr, bf16* __restrict__ Wob,
    bf16* __restrict__ Wf1t, bf16* __restrict__ Wf2t,
    bf16* __restrict__ bqvr, bf16* __restrict__ bob,
    bf16* __restrict__ bf1b, bf16* __restrict__ bf2b,
    const int* __restrict__ flagp)
{
    const int f32 = *flagp;
    int bid = blockIdx.x;
    if (bid < 4096) {
        int gid = bid * 256 + threadIdx.x;             // 0..1048575
        int row_in = gid >> 6;                         // s*8+b
        int d8 = (gid & 63) * 8;
        int s = row_in >> 3, b = row_in & 7;
        long src = (long)row_in * 512 + d8;
        long dst = ((long)b * SEQ + s) * 512 + d8;
        if (f32) {
            const float* xf = (const float*)x;
            float4 a = *(const float4*)(xf + src);
            float4 c = *(const float4*)(xf + src + 4);
            u32 o[4] = { pack2(a.x,a.y), pack2(a.z,a.w), pack2(c.x,c.y), pack2(c.z,c.w) };
            *(uint4*)(xb + dst) = *(uint4*)o;
        } else {
            *(uint4*)(xb + dst) = *(const uint4*)((const bf16*)x + src);
        }
        return;
    }
    long g = (long)(bid - 4096) * 256 + threadIdx.x;   // < 3150336
    if (g < 786432) {
        if (g < 262144) Wqvr[g] = f2b(ldE(Wq, g, f32) * LOG2E);   // Q scaled
        else if (g < 524288) Wqvr[g] = f2b(ldE(Wv, g & 262143, f32));
        else Wqvr[g] = f2b(ldE(Wr, g & 262143, f32));
    } else if (g < 1048576) {
        long j = g - 786432;
        Wob[j] = f2b(ldE(Wo, j, f32));
    } else if (g < 2097152) {
        long j = g - 1048576;
        long n = j >> 9, k = j & 511;
        Wf1t[j] = f2b(ldE(Wf1, k * 2048 + n, f32));
    } else if (g < 3145728) {
        long j = g - 2097152;
        long n = j >> 11, k = j & 2047;
        Wf2t[j] = f2b(ldE(Wf2, k * 512 + n, f32));
    } else {
        long j = g - 3145728;
        if (j < 512)       bqvr[j]      = f2b(ldE(bq, j, f32) * LOG2E);
        else if (j < 1024) bqvr[j]      = f2b(ldE(bv, j - 512, f32));
        else if (j < 1536) bqvr[j]      = f2b(ldE(br, j - 1024, f32));
        else if (j < 2048) bob[j-1536]  = f2b(ldE(bo, j - 1536, f32));
        else if (j < 4096) bf1b[j-2048] = f2b(ldE(bf1, j - 2048, f32));
        else if (j < 4608) bf2b[j-4096] = f2b(ldE(bf2, j - 4096, f32));
    }
}

// ---------------------------------------------------------------------------
// MFMA GEMM body, BK=64 as two 32-K panels (async16 lane-order preserved;
// per-panel read addressing identical to the verified BK=32 structure).
// As/Bs are [2][128][32] element panels (16 KB each array).
// ---------------------------------------------------------------------------
template<bool RELU>
__device__ __forceinline__ void gemm_body(
    const bf16* __restrict__ A, const bf16* __restrict__ W,
    const bf16* __restrict__ bias, bf16* __restrict__ C,
    int K, int lda, int ldc, int bx, int by, bf16* As, bf16* Bs)
{
    const int tid = threadIdx.x;
    const int w = tid >> 6, lane = tid & 63;
    const int li = lane & 15, quad = lane >> 4;
    const int m0 = bx * 128, n0 = by * 128;
    const int wm = (w >> 1) * 64, wn = (w & 1) * 64;
    const int srow = lane >> 2, scol = (lane & 3) * 8;

    f32x4 acc[4][4];
    const f32x4 z4 = {0.f, 0.f, 0.f, 0.f};
    #pragma unroll
    for (int i = 0; i < 4; i++)
        #pragma unroll
        for (int j = 0; j < 4; j++) acc[i][j] = z4;

    const bf16* ga = A + (long)(m0 + w * 32 + srow) * lda + scol;
    const bf16* gb = W + (long)(n0 + w * 32 + srow) * K + scol;
    bf16* lA0 = &As[(w * 32) * 32];
    bf16* lA1 = &As[(w * 32 + 16) * 32];
    bf16* lB0 = &Bs[(w * 32) * 32];
    bf16* lB1 = &Bs[(w * 32 + 16) * 32];

    for (int k0 = 0; k0 < K; k0 += 64) {
        __syncthreads();
        async16(lA0, ga);
        async16(lA1, ga + (long)16 * lda);
        async16(lA0 + 4096, ga + 32);
        async16(lA1 + 4096, ga + 32 + (long)16 * lda);
        async16(lB0, gb);
        async16(lB1, gb + (long)16 * K);
        async16(lB0 + 4096, gb + 32);
        async16(lB1 + 4096, gb + 32 + (long)16 * K);
        ga += 64; gb += 64;
        __syncthreads();
        #pragma unroll
        for (int ks = 0; ks < 2; ks++) {
            short8 af[4], bfr[4];
            #pragma unroll
            for (int t = 0; t < 4; t++)
                af[t] = *(const short8*)&As[ks * 4096 + (wm + t * 16 + li) * 32 + quad * 8];
            #pragma unroll
            for (int t = 0; t < 4; t++)
                bfr[t] = *(const short8*)&Bs[ks * 4096 + (wn + t * 16 + li) * 32 + quad * 8];
            #pragma unroll
            for (int i = 0; i < 4; i++)
                #pragma unroll
                for (int j = 0; j < 4; j++)
                    acc[i][j] = __builtin_amdgcn_mfma_f32_16x16x32_bf16(
                        af[i], bfr[j], acc[i][j], 0, 0, 0);
        }
    }

    #pragma unroll
    for (int i = 0; i < 4; i++) {
        #pragma unroll
        for (int j = 0; j < 4; j++) {
            int col = n0 + wn + j * 16 + li;
            float bb = b2f(bias[col]);
            #pragma unroll
            for (int r = 0; r < 4; r++) {
                int row = m0 + wm + i * 16 + quad * 4 + r;
                float v = acc[i][j][r] + bb;
                if (RELU) v = fmaxf(v, 0.f);
                C[(long)row * ldc + col] = f2b(v);
            }
        }
    }
}

template<bool RELU>
__global__ __launch_bounds__(256) void mfma_gemm(
    const bf16* __restrict__ A, const bf16* __restrict__ W,
    const bf16* __restrict__ bias, bf16* __restrict__ C,
    int K, int lda, int ldc)
{
    __shared__ bf16 As[8192];
    __shared__ bf16 Bs[8192];
    gemm_body<RELU>(A, W, bias, C, K, lda, ldc, blockIdx.x, blockIdx.y, As, Bs);
}

// ---------------------------------------------------------------------------
// Recurrence body (verified round 4/6). Stores h*0.125 (exp2-domain prescale).
// ---------------------------------------------------------------------------
__device__ __forceinline__ void recur_body(bf16* __restrict__ QVR,
                                           const void* __restrict__ Wh,
                                           int f32, int idx)
{
    int b = idx >> 9, o = idx & 511;
    float w = 0.0f;
    #pragma unroll
    for (int k = 0; k < DK; k++) w += ldE(Wh, (long)o * DK + k, f32);
    const float w2 = w * LOG2E2;
    bf16* base = QVR + (long)b * SEQ * 1536 + 1024 + o;

    const int PF = 32;
    float buf[PF];
    #pragma unroll
    for (int i = 0; i < PF; i++)
        buf[i] = b2f(base[(long)i * 1536]) * LOG2E2;

    float h = 0.0f;
    for (int s = 0; s < SEQ; s += PF) {
        float nbuf[PF];
        if (s + PF < SEQ) {
            #pragma unroll
            for (int i = 0; i < PF; i++)
                nbuf[i] = b2f(base[(long)(s + PF + i) * 1536]) * LOG2E2;
        }
        #pragma unroll
        for (int i = 0; i < PF; i++) {
            float xx = fmaf(h, w2, buf[i]);            // 2*log2e*(h*w + r)
            float e  = __builtin_amdgcn_exp2f(xx);
            float d  = __builtin_amdgcn_rcpf(e + 1.0f);
            h = fmaf(-2.0f, d, 1.0f);                  // tanh
            base[(long)(s + i) * 1536] = f2b(h * 0.125f);  // store pre-scaled
        }
        #pragma unroll
        for (int i = 0; i < PF; i++) buf[i] = nbuf[i];
    }
}

// ---------------------------------------------------------------------------
// Fused: blocks 0..15 recurrence; blocks 16..1039 Q|V projection.
// ---------------------------------------------------------------------------
__global__ __launch_bounds__(256) void fused_qv_recur(
    const bf16* __restrict__ xb, const bf16* __restrict__ Wqvr,
    const bf16* __restrict__ bqvr, bf16* __restrict__ QVR,
    const void* __restrict__ Wh, const int* __restrict__ flagp)
{
    __shared__ bf16 As[8192];
    __shared__ bf16 Bs[8192];
    if (blockIdx.x < 16) {
        recur_body(QVR, Wh, *flagp, blockIdx.x * 256 + threadIdx.x);
    } else {
        int bx = blockIdx.x - 16;
        gemm_body<false>(xb, Wqvr, bqvr, QVR, 512, 512, 1536,
                         bx & 127, bx >> 7, As, Bs);
    }
}

// ---------------------------------------------------------------------------
// V^T precompute: QVR V-slice [b][s][512+h*64+d] -> VTg[bh][d][s'], where
// s' applies the attention XOR swizzle within each 32-key block:
// group' = group ^ ((d>>3)&3) on aligned 8-key groups. This makes the attn
// V staging a pure async16 that lands bit-identical to the verified
// swizzled LDS layout.
// ---------------------------------------------------------------------------
__global__ __launch_bounds__(256) void vt_kernel(const bf16* __restrict__ QVR,
                                                 bf16* __restrict__ VTg)
{
    __shared__ bf16 Ls[64 * 72];   // [s][d], pad 8
    int bh = blockIdx.y, b = bh >> 3, h = bh & 7;
    int s0 = blockIdx.x * 64;
    int t = threadIdx.x;
    #pragma unroll
    for (int i = 0; i < 2; i++) {
        int item = t + i * 256;
        int s = item >> 3, d8 = (item & 7) * 8;
        uint4 v = *(const uint4*)&QVR[((long)(b * SEQ + s0 + s)) * 1536 + 512 + h * 64 + d8];
        *(uint2*)&Ls[s * 72 + d8]     = make_uint2(v.x, v.y);
        *(uint2*)&Ls[s * 72 + d8 + 4] = make_uint2(v.z, v.w);
    }
    __syncthreads();
    #pragma unroll
    for (int i = 0; i < 2; i++) {
        int item = t + i * 256;
        int d = item >> 3, sg = item & 7;
        bf16 tmp[8];
        #pragma unroll
        for (int j = 0; j < 8; j++) tmp[j] = Ls[(sg * 8 + j) * 72 + d];
        int sgp = (sg & 4) | ((sg & 3) ^ ((d >> 3) & 3));
        *(uint4*)&VTg[((long)bh * 64 + d) * 2048 + s0 + sgp * 8] = *(uint4*)tmp;
    }
}

// ---------------------------------------------------------------------------
// MFMA flash attention, round-7: 512-thread blocks (8 waves, 256 q-rows).
// Per-wave math identical to verified round-6; waves 0-3 stage K via async16,
// waves 4-7 stage V via async16 from pre-swizzled VTg (no scatter).
// ---------------------------------------------------------------------------
__global__ __launch_bounds__(512) void attn_mfma(const bf16* __restrict__ QVR,
                                                 const bf16* __restrict__ VTg,
                                                 bf16* __restrict__ O)
{
    __shared__ bf16 Kt[2 * 64 * 32];      // [ks][key][32d] unpadded
    __shared__ bf16 Vt[2 * 64 * 32];      // [ks][d][32key], swizzled (from VTg)
    __shared__ bf16 Pl[8 * 32 * 72];      // per-wave P [qrow][key], pad 72
    const int tid = threadIdx.x;
    const int w = tid >> 6, lane = tid & 63;
    const int li = lane & 15, quad = lane >> 4;
    const int bh = blockIdx.y;
    const int b = bh >> 3, hd = bh & 7;
    const int q0 = blockIdx.x * 256;
    const int qw = q0 + w * 32;                    // wave's q base
    const long rowb = (long)b * SEQ;
    const bf16* Qb = QVR + hd * DK;
    const bf16* Hb = QVR + 1024 + hd * DK;
    bf16* Pw = &Pl[w * 32 * 72];
    const f32x4 z4 = {0.f, 0.f, 0.f, 0.f};

    short8 ones;
    #pragma unroll
    for (int i = 0; i < 8; i++) ones[i] = (short)0x3F80;   // bf16 1.0

    // Q as A-operand fragments (verified mapping)
    short8 qa[2][2];
    #pragma unroll
    for (int mt = 0; mt < 2; mt++)
        #pragma unroll
        for (int ks = 0; ks < 2; ks++)
            qa[mt][ks] = *(const short8*)&Qb[(rowb + qw + mt * 16 + li) * 1536
                                             + ks * 32 + quad * 8];

    f32x4 oacc[2][4];
    f32x4 lacc[2];
    #pragma unroll
    for (int mt = 0; mt < 2; mt++) {
        #pragma unroll
        for (int dt = 0; dt < 4; dt++) oacc[mt][dt] = z4;
        lacc[mt] = z4;
    }

    for (int kt = 0; kt < SEQ; kt += 64) {
        __syncthreads();
        if (w < 4) {
            // K/H rows w*16..w*16+15, both 32-d panels
            const bf16* gk = Hb + (rowb + kt + w * 16 + (lane >> 2)) * 1536
                             + (lane & 3) * 8;
            async16(&Kt[w * 512], gk);
            async16(&Kt[2048 + w * 512], gk + 32);
        } else {
            // V^T rows d = wv*16..+15, both 32-key panels (pre-swizzled)
            int wv = w - 4;
            const bf16* gv = VTg + ((long)bh * 64 + wv * 16 + (lane >> 2)) * 2048
                             + kt + (lane & 3) * 8;
            async16(&Vt[wv * 512], gv);
            async16(&Vt[2048 + wv * 512], gv + 32);
        }
        __syncthreads();

        // ---- S = Q K^T  (exp2-domain: Q *= log2e, H *= 1/8) ----
        f32x4 sa[2][4];
        #pragma unroll
        for (int mt = 0; mt < 2; mt++)
            #pragma unroll
            for (int nt = 0; nt < 4; nt++) sa[mt][nt] = z4;
        #pragma unroll
        for (int ks = 0; ks < 2; ks++) {
            short8 kb[4];
            #pragma unroll
            for (int nt = 0; nt < 4; nt++)
                kb[nt] = *(const short8*)&Kt[ks * 2048 + (nt * 16 + li) * 32 + quad * 8];
            #pragma unroll
            for (int mt = 0; mt < 2; mt++)
                #pragma unroll
                for (int nt = 0; nt < 4; nt++)
                    sa[mt][nt] = __builtin_amdgcn_mfma_f32_16x16x32_bf16(
                        qa[mt][ks], kb[nt], sa[mt][nt], 0, 0, 0);
        }

        // ---- p = exp2(s [+ log2e]); write P; l via MFMA ----
        bool nomask  = (kt + 63 <= qw);        // max key <= min q
        bool allmask = (kt > qw + 31);         // min key > max q
        if (nomask || allmask) {
            float MB = allmask ? MC2 : 0.0f;
            #pragma unroll
            for (int mt = 0; mt < 2; mt++)
                #pragma unroll
                for (int nt = 0; nt < 4; nt++) {
                    f32x4 s = sa[mt][nt];
                    #pragma unroll
                    for (int r = 0; r < 4; r++) {
                        float p = __builtin_amdgcn_exp2f(s[r] + MB);
                        Pw[(mt * 16 + quad * 4 + r) * 72 + nt * 16 + li] = f2b(p);
                    }
                }
        } else {
            #pragma unroll
            for (int mt = 0; mt < 2; mt++) {
                int qrow = qw + mt * 16 + quad * 4;     // + r below
                #pragma unroll
                for (int nt = 0; nt < 4; nt++) {
                    int key = kt + nt * 16 + li;
                    f32x4 s = sa[mt][nt];
                    #pragma unroll
                    for (int r = 0; r < 4; r++) {
                        float arg = (key > qrow + r) ? s[r] + MC2 : s[r];
                        float p = __builtin_amdgcn_exp2f(arg);
                        Pw[(mt * 16 + quad * 4 + r) * 72 + nt * 16 + li] = f2b(p);
                    }
                }
            }
        }

        // ---- O += P V ;  l += P 1 (matrix pipe) ----
        #pragma unroll
        for (int ks = 0; ks < 2; ks++) {
            short8 vbf[4], pa[2];
            #pragma unroll
            for (int dt = 0; dt < 4; dt++) {
                int d = dt * 16 + li;
                int sw = ((d >> 3) & 3) << 3;
                vbf[dt] = *(const short8*)&Vt[ks * 2048 + d * 32 + ((quad * 8) ^ sw)];
            }
            #pragma unroll
            for (int mt = 0; mt < 2; mt++)
                pa[mt] = *(const short8*)&Pw[(mt * 16 + li) * 72 + ks * 32 + quad * 8];
            #pragma unroll
            for (int mt = 0; mt < 2; mt++) {
                lacc[mt] = __builtin_amdgcn_mfma_f32_16x16x32_bf16(
                    pa[mt], ones, lacc[mt], 0, 0, 0);
                #pragma unroll
                for (int dt = 0; dt < 4; dt++)
                    oacc[mt][dt] = __builtin_amdgcn_mfma_f32_16x16x32_bf16(
                        pa[mt], vbf[dt], oacc[mt][dt], 0, 0, 0);
            }
        }
    }

    #pragma unroll
    for (int mt = 0; mt < 2; mt++)
        #pragma unroll
        for (int r = 0; r < 4; r++) {
            float inv = 1.0f / lacc[mt][r];
            long row = rowb + qw + mt * 16 + quad * 4 + r;
            #pragma unroll
            for (int dt = 0; dt < 4; dt++)
                O[row * 512 + hd * 64 + dt * 16 + li] = f2b(oacc[mt][dt][r] * inv);
        }
}

// ---------------------------------------------------------------------------
// LN1: xb + AO (both bf16 plain) -> X1 bf16 plain (u32-vectorized)
// ---------------------------------------------------------------------------
__global__ __launch_bounds__(256) void ln1_kernel(const bf16* __restrict__ xb,
                                                  const bf16* __restrict__ ao,
                                                  const void* __restrict__ g,
                                                  const void* __restrict__ beta,
                                                  bf16* __restrict__ x1,
                                                  const int* __restrict__ flagp)
{
    const int f32 = *flagp;
    long base = (long)blockIdx.x * 512;
    int tid = threadIdx.x;
    int d2 = tid * 2;
    float x0, x1v, a0, a1;
    unpack2(*(const u32*)&xb[base + d2], x0, x1v);
    unpack2(*(const u32*)&ao[base + d2], a0, a1);
    float v0 = x0 + a0, v1 = x1v + a1;
    float s1 = v0 + v1;
    float s2 = v0 * v0 + v1 * v1;
    #pragma unroll
    for (int off = 32; off > 0; off >>= 1) {
        s1 += __shfl_down(s1, off);
        s2 += __shfl_down(s2, off);
    }
    __shared__ float w1[4], w2[4];
    int wid = tid >> 6, lane = tid & 63;
    if (lane == 0) { w1[wid] = s1; w2[wid] = s2; }
    __syncthreads();
    float t1 = w1[0] + w1[1] + w1[2] + w1[3];
    float t2 = w2[0] + w2[1] + w2[2] + w2[3];
    float mu = t1 * (1.0f / DMODEL);
    float var = t2 * (1.0f / DMODEL) - mu * mu;
    float rs = rsqrtf(var + 1e-5f);
    float r0 = (v0 - mu) * rs * ldE(g, d2, f32) + ldE(beta, d2, f32);
    float r1 = (v1 - mu) * rs * ldE(g, d2 + 1, f32) + ldE(beta, d2 + 1, f32);
    *(u32*)&x1[base + d2] = pack2(r0, r1);
}

// ---------------------------------------------------------------------------
// LN2: X1 + FF2 -> d_out (external dtype, (S,B,D) layout)
// ---------------------------------------------------------------------------
__global__ __launch_bounds__(256) void ln2_kernel(const bf16* __restrict__ x1,
                                                  const bf16* __restrict__ ff2,
                                                  const void* __restrict__ g,
                                                  const void* __restrict__ beta,
                                                  void* __restrict__ outp,
                                                  const int* __restrict__ flagp)
{
    const int f32 = *flagp;
    int m = blockIdx.x;                 // b*SEQ + s
    int b = m >> 11, s = m & 2047;
    long plain = (long)m * 512;
    long funny = ((long)s * BATCH + b) * 512;
    int tid = threadIdx.x;
    int d2 = tid * 2;
    float x0, x1v, a0, a1;
    unpack2(*(const u32*)&x1[plain + d2], x0, x1v);
    unpack2(*(const u32*)&ff2[plain + d2], a0, a1);
    float v0 = x0 + a0, v1 = x1v + a1;
    float s1 = v0 + v1;
    float s2 = v0 * v0 + v1 * v1;
    #pragma unroll
    for (int off = 32; off > 0; off >>= 1) {
        s1 += __shfl_down(s1, off);
        s2 += __shfl_down(s2, off);
    }
    __shared__ float w1[4], w2[4];
    int wid = tid >> 6, lane = tid & 63;
    if (lane == 0) { w1[wid] = s1; w2[wid] = s2; }
    __syncthreads();
    float t1 = w1[0] + w1[1] + w1[2] + w1[3];
    float t2 = w2[0] + w2[1] + w2[2] + w2[3];
    float mu = t1 * (1.0f / DMODEL);
    float var = t2 * (1.0f / DMODEL) - mu * mu;
    float rs = rsqrtf(var + 1e-5f);
    float r0 = (v0 - mu) * rs * ldE(g, d2, f32) + ldE(beta, d2, f32);
    float r1 = (v1 - mu) * rs * ldE(g, d2 + 1, f32) + ldE(beta, d2 + 1, f32);
    if (f32) {
        ((float*)outp)[funny + d2]     = r0;
        ((float*)outp)[funny + d2 + 1] = r1;
    } else {
        *(u32*)&((bf16*)outp)[funny + d2] = pack2(r0, r1);
    }
}

// ---------------------------------------------------------------------------
extern "C" void kernel_launch(void* const* d_in, const int* in_sizes, int n_in,
                              void* d_out, int out_size, void* d_ws, size_t ws_size,
                              hipStream_t stream)
{
    (void)in_sizes; (void)n_in; (void)out_size; (void)ws_size;
    const void* x = d_in[0];

    // bf16 workspace layout (elements):
    bf16* W    = (bf16*)d_ws;
    bf16* xb   = W;                       // [0, 8M)   dead after LN1
    bf16* QVR  = W + (8u  << 20);         // [8M, 32M) Q|V|R cols, dead after attn
    bf16* Ob   = W + (32u << 20);         // [32M,40M) dead after Wo gemm
    bf16* VTg  = W + (40u << 20);         // [40M,48M) V^T swizzled, dead after attn
    bf16* AO   = W + (40u << 20);         // same region, written after attn
    bf16* X1   = W + (8u  << 20);         // reuse QVR head, alive until LN2
    bf16* FFH  = W + (16u << 20);         // [16M,48M) after LN1
    bf16* FF2  = W;                       // reuse xb
    int*  flag = (int*)((char*)d_ws + (size_t)96 * 1024 * 1024);
    bf16* Wt   = (bf16*)((char*)d_ws + (size_t)96 * 1024 * 1024 + 16);
    bf16* Wqvr = Wt;                      // [1536][512]
    bf16* Wob  = Wt + 786432;             // [512][512]
    bf16* Wf1t = Wt + 1048576;            // [2048][512]
    bf16* Wf2t = Wt + 2097152;            // [512][2048]
    bf16* bqvr = Wt + 3145728;
    bf16* bob  = Wt + 3147264;
    bf16* bf1b = Wt + 3147776;
    bf16* bf2b = Wt + 3149824;

    dim3 blk(256);
    probe_kernel<<<1, blk, 0, stream>>>(x, flag);
    prep_all<<<16402, blk, 0, stream>>>(
        x, xb,
        d_in[1], d_in[3], d_in[5], d_in[8], d_in[12], d_in[14],
        d_in[2], d_in[4], d_in[6], d_in[9], d_in[13], d_in[15],
        Wqvr, Wob, Wf1t, Wf2t, bqvr, bob, bf1b, bf2b, flag);

    // R projection only: cols 1024..1535 of QVR
    mfma_gemm<false><<<dim3(128, 4), blk, 0, stream>>>(
        xb, Wqvr + 1024 * 512, bqvr + 1024, QVR + 1024, 512, 512, 1536);

    // fused: recurrence (blocks 0..15) + Q|V projection (blocks 16..1039)
    fused_qv_recur<<<1040, blk, 0, stream>>>(xb, Wqvr, bqvr, QVR, d_in[7], flag);

    // V^T precompute (swizzled) into VTg
    vt_kernel<<<dim3(32, 64), blk, 0, stream>>>(QVR, VTg);

    // attention: 512-thread blocks, 256 q-rows each
    attn_mfma<<<dim3(8, 64), dim3(512), 0, stream>>>(QVR, VTg, Ob);

    // Wo projection
    mfma_gemm<false><<<dim3(128, 4), blk, 0, stream>>>(Ob, Wob, bob, AO, 512, 512, 512);

    // LN1
    ln1_kernel<<<MROWS, blk, 0, stream>>>(xb, AO, d_in[10], d_in[11], X1, flag);

    // FF1 (relu)
    mfma_gemm<true><<<dim3(128, 16), blk, 0, stream>>>(X1, Wf1t, bf1b, FFH, 512, 512, 2048);

    // FF2
    mfma_gemm<false><<<dim3(128, 4), blk, 0, stream>>>(FFH, Wf2t, bf2b, FF2, 2048, 2048, 512);

    // LN2 -> d_out
    ln2_kernel<<<MROWS, blk, 0, stream>>>(X1, FF2, d_in[16], d_in[17], d_out, flag);
}

// Round 8
// 532.390 us; speedup vs baseline: 8.3676x; 1.0160x over previous
//
#include <hip/hip_runtime.h>
#include <hip/hip_bf16.h>
#include <math.h>

#define SEQ    2048
#define BATCH  8
#define DMODEL 512
#define NHEADS 8
#define DK     64
#define DFF    2048
#define MROWS  16384

typedef __hip_bfloat16 bf16;
typedef unsigned int   u32;
typedef unsigned short u16;
typedef __attribute__((ext_vector_type(8))) short short8;   // 8 bf16 = 4 VGPR
typedef __attribute__((ext_vector_type(4))) float f32x4;

#define LOG2E  1.4426950408889634f
#define LOG2E2 2.8853900817779268f   // 2*log2(e)
#define MC2    1.4426950408889634f   // log2(e) : +1.0-mask in exp2 domain

__device__ __forceinline__ float b2f(bf16 v) { return __bfloat162float(v); }
__device__ __forceinline__ bf16  f2b(float f) { return __float2bfloat16(f); }
__device__ __forceinline__ u16 f2u(float f) { bf16 h = __float2bfloat16(f); return *(u16*)&h; }
__device__ __forceinline__ u32 pack2(float a, float b) {
    return ((u32)f2u(b) << 16) | (u32)f2u(a);
}
__device__ __forceinline__ void unpack2(u32 u, float& a, float& b) {
    a = __uint_as_float(u << 16);
    b = __uint_as_float(u & 0xFFFF0000u);
}
// external-tensor load: dtype decided at runtime by probe flag (0=bf16, 1=fp32)
__device__ __forceinline__ float ldE(const void* p, long off, int f32) {
    return f32 ? ((const float*)p)[off] : b2f(((const bf16*)p)[off]);
}
// async global->LDS, 16B per lane; lds base must be wave-uniform
__device__ __forceinline__ void async16(bf16* lds, const bf16* g) {
    __builtin_amdgcn_global_load_lds(
        (const __attribute__((address_space(1))) void*)g,
        (__attribute__((address_space(3))) void*)lds, 16, 0, 0);
}

// ---------------------------------------------------------------------------
// Dtype probe (verified round 2): flag=1 means fp32 inputs.
// ---------------------------------------------------------------------------
__global__ __launch_bounds__(256) void probe_kernel(const void* __restrict__ x,
                                                    int* __restrict__ flag)
{
    int tid = threadIdx.x;
    const u16* u = (const u16*)x;
    int cnt = 0;
    #pragma unroll
    for (int i = 0; i < 8; i++) {
        u16 e = u[tid * 8 + i];
        float v = __uint_as_float(((u32)e) << 16);
        float a = fabsf(v);
        if (a > 9.313226e-10f && a < 1.0737418e9f) cnt++;
    }
    __shared__ int sh[256];
    sh[tid] = cnt;
    __syncthreads();
    for (int s = 128; s > 0; s >>= 1) {
        if (tid < s) sh[tid] += sh[tid + s];
        __syncthreads();
    }
    if (tid == 0) *flag = (sh[0] < 1700) ? 1 : 0;
}

// ---------------------------------------------------------------------------
// Merged prep: blocks 0..4095 convert x; blocks 4096.. pack weights.
// Wq,bq pre-scaled by log2e (softmax scale folded into Q).
// ---------------------------------------------------------------------------
__global__ __launch_bounds__(256) void prep_all(
    const void* x, bf16* __restrict__ xb,
    const void* Wq, const void* Wv, const void* Wr, const void* Wo,
    const void* Wf1, const void* Wf2,
    const void* bq, const void* bv, const void* br, const void* bo,
    const void* bf1, const void* bf2,
    bf16* __restrict__ Wqvr, bf16* __restrict__ Wob,
    bf16* __restrict__ Wf1t, bf16* __restrict__ Wf2t,
    bf16* __restrict__ bqvr, bf16* __restrict__ bob,
    bf16* __restrict__ bf1b, bf16* __restrict__ bf2b,
    const int* __restrict__ flagp)
{
    const int f32 = *flagp;
    int bid = blockIdx.x;
    if (bid < 4096) {
        int gid = bid * 256 + threadIdx.x;             // 0..1048575
        int row_in = gid >> 6;                         // s*8+b
        int d8 = (gid & 63) * 8;
        int s = row_in >> 3, b = row_in & 7;
        long src = (long)row_in * 512 + d8;
        long dst = ((long)b * SEQ + s) * 512 + d8;
        if (f32) {
            const float* xf = (const float*)x;
            float4 a = *(const float4*)(xf + src);
            float4 c = *(const float4*)(xf + src + 4);
            u32 o[4] = { pack2(a.x,a.y), pack2(a.z,a.w), pack2(c.x,c.y), pack2(c.z,c.w) };
            *(uint4*)(xb + dst) = *(uint4*)o;
        } else {
            *(uint4*)(xb + dst) = *(const uint4*)((const bf16*)x + src);
        }
        return;
    }
    long g = (long)(bid - 4096) * 256 + threadIdx.x;   // < 3150336
    if (g < 786432) {
        if (g < 262144) Wqvr[g] = f2b(ldE(Wq, g, f32) * LOG2E);   // Q scaled
        else if (g < 524288) Wqvr[g] = f2b(ldE(Wv, g & 262143, f32));
        else Wqvr[g] = f2b(ldE(Wr, g & 262143, f32));
    } else if (g < 1048576) {
        long j = g - 786432;
        Wob[j] = f2b(ldE(Wo, j, f32));
    } else if (g < 2097152) {
        long j = g - 1048576;
        long n = j >> 9, k = j & 511;
        Wf1t[j] = f2b(ldE(Wf1, k * 2048 + n, f32));
    } else if (g < 3145728) {
        long j = g - 2097152;
        long n = j >> 11, k = j & 2047;
        Wf2t[j] = f2b(ldE(Wf2, k * 512 + n, f32));
    } else {
        long j = g - 3145728;
        if (j < 512)       bqvr[j]      = f2b(ldE(bq, j, f32) * LOG2E);
        else if (j < 1024) bqvr[j]      = f2b(ldE(bv, j - 512, f32));
        else if (j < 1536) bqvr[j]      = f2b(ldE(br, j - 1024, f32));
        else if (j < 2048) bob[j-1536]  = f2b(ldE(bo, j - 1536, f32));
        else if (j < 4096) bf1b[j-2048] = f2b(ldE(bf1, j - 2048, f32));
        else if (j < 4608) bf2b[j-4096] = f2b(ldE(bf2, j - 4096, f32));
    }
}

// ---------------------------------------------------------------------------
// MFMA GEMM body, BK=64 as two 32-K panels (verified round 7).
// ---------------------------------------------------------------------------
template<bool RELU>
__device__ __forceinline__ void gemm_body(
    const bf16* __restrict__ A, const bf16* __restrict__ W,
    const bf16* __restrict__ bias, bf16* __restrict__ C,
    int K, int lda, int ldc, int bx, int by, bf16* As, bf16* Bs)
{
    const int tid = threadIdx.x;
    const int w = tid >> 6, lane = tid & 63;
    const int li = lane & 15, quad = lane >> 4;
    const int m0 = bx * 128, n0 = by * 128;
    const int wm = (w >> 1) * 64, wn = (w & 1) * 64;
    const int srow = lane >> 2, scol = (lane & 3) * 8;

    f32x4 acc[4][4];
    const f32x4 z4 = {0.f, 0.f, 0.f, 0.f};
    #pragma unroll
    for (int i = 0; i < 4; i++)
        #pragma unroll
        for (int j = 0; j < 4; j++) acc[i][j] = z4;

    const bf16* ga = A + (long)(m0 + w * 32 + srow) * lda + scol;
    const bf16* gb = W + (long)(n0 + w * 32 + srow) * K + scol;
    bf16* lA0 = &As[(w * 32) * 32];
    bf16* lA1 = &As[(w * 32 + 16) * 32];
    bf16* lB0 = &Bs[(w * 32) * 32];
    bf16* lB1 = &Bs[(w * 32 + 16) * 32];

    for (int k0 = 0; k0 < K; k0 += 64) {
        __syncthreads();
        async16(lA0, ga);
        async16(lA1, ga + (long)16 * lda);
        async16(lA0 + 4096, ga + 32);
        async16(lA1 + 4096, ga + 32 + (long)16 * lda);
        async16(lB0, gb);
        async16(lB1, gb + (long)16 * K);
        async16(lB0 + 4096, gb + 32);
        async16(lB1 + 4096, gb + 32 + (long)16 * K);
        ga += 64; gb += 64;
        __syncthreads();
        #pragma unroll
        for (int ks = 0; ks < 2; ks++) {
            short8 af[4], bfr[4];
            #pragma unroll
            for (int t = 0; t < 4; t++)
                af[t] = *(const short8*)&As[ks * 4096 + (wm + t * 16 + li) * 32 + quad * 8];
            #pragma unroll
            for (int t = 0; t < 4; t++)
                bfr[t] = *(const short8*)&Bs[ks * 4096 + (wn + t * 16 + li) * 32 + quad * 8];
            #pragma unroll
            for (int i = 0; i < 4; i++)
                #pragma unroll
                for (int j = 0; j < 4; j++)
                    acc[i][j] = __builtin_amdgcn_mfma_f32_16x16x32_bf16(
                        af[i], bfr[j], acc[i][j], 0, 0, 0);
        }
    }

    #pragma unroll
    for (int i = 0; i < 4; i++) {
        #pragma unroll
        for (int j = 0; j < 4; j++) {
            int col = n0 + wn + j * 16 + li;
            float bb = b2f(bias[col]);
            #pragma unroll
            for (int r = 0; r < 4; r++) {
                int row = m0 + wm + i * 16 + quad * 4 + r;
                float v = acc[i][j][r] + bb;
                if (RELU) v = fmaxf(v, 0.f);
                C[(long)row * ldc + col] = f2b(v);
            }
        }
    }
}

template<bool RELU>
__global__ __launch_bounds__(256) void mfma_gemm(
    const bf16* __restrict__ A, const bf16* __restrict__ W,
    const bf16* __restrict__ bias, bf16* __restrict__ C,
    int K, int lda, int ldc)
{
    __shared__ bf16 As[8192];
    __shared__ bf16 Bs[8192];
    gemm_body<RELU>(A, W, bias, C, K, lda, ldc, blockIdx.x, blockIdx.y, As, Bs);
}

// ---------------------------------------------------------------------------
// Recurrence body (verified round 4/6). Stores h*0.125 (exp2-domain prescale).
// ---------------------------------------------------------------------------
__device__ __forceinline__ void recur_body(bf16* __restrict__ QVR,
                                           const void* __restrict__ Wh,
                                           int f32, int idx)
{
    int b = idx >> 9, o = idx & 511;
    float w = 0.0f;
    #pragma unroll
    for (int k = 0; k < DK; k++) w += ldE(Wh, (long)o * DK + k, f32);
    const float w2 = w * LOG2E2;
    bf16* base = QVR + (long)b * SEQ * 1536 + 1024 + o;

    const int PF = 32;
    float buf[PF];
    #pragma unroll
    for (int i = 0; i < PF; i++)
        buf[i] = b2f(base[(long)i * 1536]) * LOG2E2;

    float h = 0.0f;
    for (int s = 0; s < SEQ; s += PF) {
        float nbuf[PF];
        if (s + PF < SEQ) {
            #pragma unroll
            for (int i = 0; i < PF; i++)
                nbuf[i] = b2f(base[(long)(s + PF + i) * 1536]) * LOG2E2;
        }
        #pragma unroll
        for (int i = 0; i < PF; i++) {
            float xx = fmaf(h, w2, buf[i]);            // 2*log2e*(h*w + r)
            float e  = __builtin_amdgcn_exp2f(xx);
            float d  = __builtin_amdgcn_rcpf(e + 1.0f);
            h = fmaf(-2.0f, d, 1.0f);                  // tanh
            base[(long)(s + i) * 1536] = f2b(h * 0.125f);  // store pre-scaled
        }
        #pragma unroll
        for (int i = 0; i < PF; i++) buf[i] = nbuf[i];
    }
}

// ---------------------------------------------------------------------------
// Fused: blocks 0..15 recurrence; blocks 16..1039 Q|V projection.
// ---------------------------------------------------------------------------
__global__ __launch_bounds__(256) void fused_qv_recur(
    const bf16* __restrict__ xb, const bf16* __restrict__ Wqvr,
    const bf16* __restrict__ bqvr, bf16* __restrict__ QVR,
    const void* __restrict__ Wh, const int* __restrict__ flagp)
{
    __shared__ bf16 As[8192];
    __shared__ bf16 Bs[8192];
    if (blockIdx.x < 16) {
        recur_body(QVR, Wh, *flagp, blockIdx.x * 256 + threadIdx.x);
    } else {
        int bx = blockIdx.x - 16;
        gemm_body<false>(xb, Wqvr, bqvr, QVR, 512, 512, 1536,
                         bx & 127, bx >> 7, As, Bs);
    }
}

// ---------------------------------------------------------------------------
// V^T precompute with pre-applied XOR swizzle (verified round 7).
// ---------------------------------------------------------------------------
__global__ __launch_bounds__(256) void vt_kernel(const bf16* __restrict__ QVR,
                                                 bf16* __restrict__ VTg)
{
    __shared__ bf16 Ls[64 * 72];   // [s][d], pad 8
    int bh = blockIdx.y, b = bh >> 3, h = bh & 7;
    int s0 = blockIdx.x * 64;
    int t = threadIdx.x;
    #pragma unroll
    for (int i = 0; i < 2; i++) {
        int item = t + i * 256;
        int s = item >> 3, d8 = (item & 7) * 8;
        uint4 v = *(const uint4*)&QVR[((long)(b * SEQ + s0 + s)) * 1536 + 512 + h * 64 + d8];
        *(uint2*)&Ls[s * 72 + d8]     = make_uint2(v.x, v.y);
        *(uint2*)&Ls[s * 72 + d8 + 4] = make_uint2(v.z, v.w);
    }
    __syncthreads();
    #pragma unroll
    for (int i = 0; i < 2; i++) {
        int item = t + i * 256;
        int d = item >> 3, sg = item & 7;
        bf16 tmp[8];
        #pragma unroll
        for (int j = 0; j < 8; j++) tmp[j] = Ls[(sg * 8 + j) * 72 + d];
        int sgp = (sg & 4) | ((sg & 3) ^ ((d >> 3) & 3));
        *(uint4*)&VTg[((long)bh * 64 + d) * 2048 + s0 + sgp * 8] = *(uint4*)tmp;
    }
}

// ---------------------------------------------------------------------------
// MFMA flash attention, round-8: 128-key barrier windows. Kt/Vt hold two
// 64-key tiles (kh=0,1); the two sub-tiles are processed sequentially inside
// one barrier window (Pl is wave-private -> no barrier between sub-tiles).
// Halves the __syncthreads+vmcnt-drain count (32 -> 16). Per-sub-tile math
// identical to verified round 7.
// ---------------------------------------------------------------------------
__global__ __launch_bounds__(512) void attn_mfma(const bf16* __restrict__ QVR,
                                                 const bf16* __restrict__ VTg,
                                                 bf16* __restrict__ O)
{
    __shared__ bf16 Kt[4 * 64 * 32];      // [kh][ks][64key][32d] unpadded
    __shared__ bf16 Vt[4 * 64 * 32];      // [kh][ks][64d][32key], swizzled
    __shared__ bf16 Pl[8 * 32 * 72];      // per-wave P [qrow][key], pad 72
    const int tid = threadIdx.x;
    const int w = tid >> 6, lane = tid & 63;
    const int li = lane & 15, quad = lane >> 4;
    const int bh = blockIdx.y;
    const int b = bh >> 3, hd = bh & 7;
    const int q0 = blockIdx.x * 256;
    const int qw = q0 + w * 32;                    // wave's q base
    const long rowb = (long)b * SEQ;
    const bf16* Qb = QVR + hd * DK;
    const bf16* Hb = QVR + 1024 + hd * DK;
    bf16* Pw = &Pl[w * 32 * 72];
    const f32x4 z4 = {0.f, 0.f, 0.f, 0.f};

    short8 ones;
    #pragma unroll
    for (int i = 0; i < 8; i++) ones[i] = (short)0x3F80;   // bf16 1.0

    // Q as A-operand fragments (verified mapping)
    short8 qa[2][2];
    #pragma unroll
    for (int mt = 0; mt < 2; mt++)
        #pragma unroll
        for (int ks = 0; ks < 2; ks++)
            qa[mt][ks] = *(const short8*)&Qb[(rowb + qw + mt * 16 + li) * 1536
                                             + ks * 32 + quad * 8];

    f32x4 oacc[2][4];
    f32x4 lacc[2];
    #pragma unroll
    for (int mt = 0; mt < 2; mt++) {
        #pragma unroll
        for (int dt = 0; dt < 4; dt++) oacc[mt][dt] = z4;
        lacc[mt] = z4;
    }

    for (int kt = 0; kt < SEQ; kt += 128) {
        __syncthreads();
        if (w < 4) {
            // K/H rows w*16..+15 for both key-halves, both 32-d panels
            const bf16* gk = Hb + (rowb + kt + w * 16 + (lane >> 2)) * 1536
                             + (lane & 3) * 8;
            async16(&Kt[w * 512],        gk);
            async16(&Kt[2048 + w * 512], gk + 32);
            const bf16* gk1 = gk + (long)64 * 1536;
            async16(&Kt[4096 + w * 512], gk1);
            async16(&Kt[6144 + w * 512], gk1 + 32);
        } else {
            // V^T rows d = wv*16..+15 for both key-halves (pre-swizzled)
            int wv = w - 4;
            const bf16* gv = VTg + ((long)bh * 64 + wv * 16 + (lane >> 2)) * 2048
                             + kt + (lane & 3) * 8;
            async16(&Vt[wv * 512],        gv);
            async16(&Vt[2048 + wv * 512], gv + 32);
            async16(&Vt[4096 + wv * 512], gv + 64);
            async16(&Vt[6144 + wv * 512], gv + 96);
        }
        __syncthreads();

        #pragma unroll
        for (int kh = 0; kh < 2; kh++) {
            const int kt2 = kt + kh * 64;
            const bf16* Kp = &Kt[kh * 4096];
            const bf16* Vp = &Vt[kh * 4096];

            // ---- S = Q K^T  (exp2-domain: Q *= log2e, H *= 1/8) ----
            f32x4 sa[2][4];
            #pragma unroll
            for (int mt = 0; mt < 2; mt++)
                #pragma unroll
                for (int nt = 0; nt < 4; nt++) sa[mt][nt] = z4;
            #pragma unroll
            for (int ks = 0; ks < 2; ks++) {
                short8 kb[4];
                #pragma unroll
                for (int nt = 0; nt < 4; nt++)
                    kb[nt] = *(const short8*)&Kp[ks * 2048 + (nt * 16 + li) * 32 + quad * 8];
                #pragma unroll
                for (int mt = 0; mt < 2; mt++)
                    #pragma unroll
                    for (int nt = 0; nt < 4; nt++)
                        sa[mt][nt] = __builtin_amdgcn_mfma_f32_16x16x32_bf16(
                            qa[mt][ks], kb[nt], sa[mt][nt], 0, 0, 0);
            }

            // ---- p = exp2(s [+ log2e]); write P; l via MFMA ----
            bool nomask  = (kt2 + 63 <= qw);       // max key <= min q
            bool allmask = (kt2 > qw + 31);        // min key > max q
            if (nomask || allmask) {
                float MB = allmask ? MC2 : 0.0f;
                #pragma unroll
                for (int mt = 0; mt < 2; mt++)
                    #pragma unroll
                    for (int nt = 0; nt < 4; nt++) {
                        f32x4 s = sa[mt][nt];
                        #pragma unroll
                        for (int r = 0; r < 4; r++) {
                            float p = __builtin_amdgcn_exp2f(s[r] + MB);
                            Pw[(mt * 16 + quad * 4 + r) * 72 + nt * 16 + li] = f2b(p);
                        }
                    }
            } else {
                #pragma unroll
                for (int mt = 0; mt < 2; mt++) {
                    int qrow = qw + mt * 16 + quad * 4;     // + r below
                    #pragma unroll
                    for (int nt = 0; nt < 4; nt++) {
                        int key = kt2 + nt * 16 + li;
                        f32x4 s = sa[mt][nt];
                        #pragma unroll
                        for (int r = 0; r < 4; r++) {
                            float arg = (key > qrow + r) ? s[r] + MC2 : s[r];
                            float p = __builtin_amdgcn_exp2f(arg);
                            Pw[(mt * 16 + quad * 4 + r) * 72 + nt * 16 + li] = f2b(p);
                        }
                    }
                }
            }

            // ---- O += P V ;  l += P 1 (matrix pipe) ----
            #pragma unroll
            for (int ks = 0; ks < 2; ks++) {
                short8 vbf[4], pa[2];
                #pragma unroll
                for (int dt = 0; dt < 4; dt++) {
                    int d = dt * 16 + li;
                    int sw = ((d >> 3) & 3) << 3;
                    vbf[dt] = *(const short8*)&Vp[ks * 2048 + d * 32 + ((quad * 8) ^ sw)];
                }
                #pragma unroll
                for (int mt = 0; mt < 2; mt++)
                    pa[mt] = *(const short8*)&Pw[(mt * 16 + li) * 72 + ks * 32 + quad * 8];
                #pragma unroll
                for (int mt = 0; mt < 2; mt++) {
                    lacc[mt] = __builtin_amdgcn_mfma_f32_16x16x32_bf16(
                        pa[mt], ones, lacc[mt], 0, 0, 0);
                    #pragma unroll
                    for (int dt = 0; dt < 4; dt++)
                        oacc[mt][dt] = __builtin_amdgcn_mfma_f32_16x16x32_bf16(
                            pa[mt], vbf[dt], oacc[mt][dt], 0, 0, 0);
                }
            }
        }
    }

    #pragma unroll
    for (int mt = 0; mt < 2; mt++)
        #pragma unroll
        for (int r = 0; r < 4; r++) {
            float inv = 1.0f / lacc[mt][r];
            long row = rowb + qw + mt * 16 + quad * 4 + r;
            #pragma unroll
            for (int dt = 0; dt < 4; dt++)
                O[row * 512 + hd * 64 + dt * 16 + li] = f2b(oacc[mt][dt][r] * inv);
        }
}

// ---------------------------------------------------------------------------
// LN1: xb + AO (both bf16 plain) -> X1 bf16 plain (u32-vectorized)
// ---------------------------------------------------------------------------
__global__ __launch_bounds__(256) void ln1_kernel(const bf16* __restrict__ xb,
                                                  const bf16* __restrict__ ao,
                                                  const void* __restrict__ g,
                                                  const void* __restrict__ beta,
                                                  bf16* __restrict__ x1,
                                                  const int* __restrict__ flagp)
{
    const int f32 = *flagp;
    long base = (long)blockIdx.x * 512;
    int tid = threadIdx.x;
    int d2 = tid * 2;
    float x0, x1v, a0, a1;
    unpack2(*(const u32*)&xb[base + d2], x0, x1v);
    unpack2(*(const u32*)&ao[base + d2], a0, a1);
    float v0 = x0 + a0, v1 = x1v + a1;
    float s1 = v0 + v1;
    float s2 = v0 * v0 + v1 * v1;
    #pragma unroll
    for (int off = 32; off > 0; off >>= 1) {
        s1 += __shfl_down(s1, off);
        s2 += __shfl_down(s2, off);
    }
    __shared__ float w1[4], w2[4];
    int wid = tid >> 6, lane = tid & 63;
    if (lane == 0) { w1[wid] = s1; w2[wid] = s2; }
    __syncthreads();
    float t1 = w1[0] + w1[1] + w1[2] + w1[3];
    float t2 = w2[0] + w2[1] + w2[2] + w2[3];
    float mu = t1 * (1.0f / DMODEL);
    float var = t2 * (1.0f / DMODEL) - mu * mu;
    float rs = rsqrtf(var + 1e-5f);
    float r0 = (v0 - mu) * rs * ldE(g, d2, f32) + ldE(beta, d2, f32);
    float r1 = (v1 - mu) * rs * ldE(g, d2 + 1, f32) + ldE(beta, d2 + 1, f32);
    *(u32*)&x1[base + d2] = pack2(r0, r1);
}

// ---------------------------------------------------------------------------
// LN2: X1 + FF2 -> d_out (external dtype, (S,B,D) layout)
// ---------------------------------------------------------------------------
__global__ __launch_bounds__(256) void ln2_kernel(const bf16* __restrict__ x1,
                                                  const bf16* __restrict__ ff2,
                                                  const void* __restrict__ g,
                                                  const void* __restrict__ beta,
                                                  void* __restrict__ outp,
                                                  const int* __restrict__ flagp)
{
    const int f32 = *flagp;
    int m = blockIdx.x;                 // b*SEQ + s
    int b = m >> 11, s = m & 2047;
    long plain = (long)m * 512;
    long funny = ((long)s * BATCH + b) * 512;
    int tid = threadIdx.x;
    int d2 = tid * 2;
    float x0, x1v, a0, a1;
    unpack2(*(const u32*)&x1[plain + d2], x0, x1v);
    unpack2(*(const u32*)&ff2[plain + d2], a0, a1);
    float v0 = x0 + a0, v1 = x1v + a1;
    float s1 = v0 + v1;
    float s2 = v0 * v0 + v1 * v1;
    #pragma unroll
    for (int off = 32; off > 0; off >>= 1) {
        s1 += __shfl_down(s1, off);
        s2 += __shfl_down(s2, off);
    }
    __shared__ float w1[4], w2[4];
    int wid = tid >> 6, lane = tid & 63;
    if (lane == 0) { w1[wid] = s1; w2[wid] = s2; }
    __syncthreads();
    float t1 = w1[0] + w1[1] + w1[2] + w1[3];
    float t2 = w2[0] + w2[1] + w2[2] + w2[3];
    float mu = t1 * (1.0f / DMODEL);
    float var = t2 * (1.0f / DMODEL) - mu * mu;
    float rs = rsqrtf(var + 1e-5f);
    float r0 = (v0 - mu) * rs * ldE(g, d2, f32) + ldE(beta, d2, f32);
    float r1 = (v1 - mu) * rs * ldE(g, d2 + 1, f32) + ldE(beta, d2 + 1, f32);
    if (f32) {
        ((float*)outp)[funny + d2]     = r0;
        ((float*)outp)[funny + d2 + 1] = r1;
    } else {
        *(u32*)&((bf16*)outp)[funny + d2] = pack2(r0, r1);
    }
}

// ---------------------------------------------------------------------------
extern "C" void kernel_launch(void* const* d_in, const int* in_sizes, int n_in,
                              void* d_out, int out_size, void* d_ws, size_t ws_size,
                              hipStream_t stream)
{
    (void)in_sizes; (void)n_in; (void)out_size; (void)ws_size;
    const void* x = d_in[0];

    // bf16 workspace layout (elements):
    bf16* W    = (bf16*)d_ws;
    bf16* xb   = W;                       // [0, 8M)   dead after LN1
    bf16* QVR  = W + (8u  << 20);         // [8M, 32M) Q|V|R cols, dead after attn
    bf16* Ob   = W + (32u << 20);         // [32M,40M) dead after Wo gemm
    bf16* VTg  = W + (40u << 20);         // [40M,48M) V^T swizzled, dead after attn
    bf16* AO   = W + (40u << 20);         // same region, written after attn
    bf16* X1   = W + (8u  << 20);         // reuse QVR head, alive until LN2
    bf16* FFH  = W + (16u << 20);         // [16M,48M) after LN1
    bf16* FF2  = W;                       // reuse xb
    int*  flag = (int*)((char*)d_ws + (size_t)96 * 1024 * 1024);
    bf16* Wt   = (bf16*)((char*)d_ws + (size_t)96 * 1024 * 1024 + 16);
    bf16* Wqvr = Wt;                      // [1536][512]
    bf16* Wob  = Wt + 786432;             // [512][512]
    bf16* Wf1t = Wt + 1048576;            // [2048][512]
    bf16* Wf2t = Wt + 2097152;            // [512][2048]
    bf16* bqvr = Wt + 3145728;
    bf16* bob  = Wt + 3147264;
    bf16* bf1b = Wt + 3147776;
    bf16* bf2b = Wt + 3149824;

    dim3 blk(256);
    probe_kernel<<<1, blk, 0, stream>>>(x, flag);
    prep_all<<<16402, blk, 0, stream>>>(
        x, xb,
        d_in[1], d_in[3], d_in[5], d_in[8], d_in[12], d_in[14],
        d_in[2], d_in[4], d_in[6], d_in[9], d_in[13], d_in[15],
        Wqvr, Wob, Wf1t, Wf2t, bqvr, bob, bf1b, bf2b, flag);

    // R projection only: cols 1024..1535 of QVR
    mfma_gemm<false><<<dim3(128, 4), blk, 0, stream>>>(
        xb, Wqvr + 1024 * 512, bqvr + 1024, QVR + 1024, 512, 512, 1536);

    // fused: recurrence (blocks 0..15) + Q|V projection (blocks 16..1039)
    fused_qv_recur<<<1040, blk, 0, stream>>>(xb, Wqvr, bqvr, QVR, d_in[7], flag);

    // V^T precompute (swizzled) into VTg
    vt_kernel<<<dim3(32, 64), blk, 0, stream>>>(QVR, VTg);

    // attention: 512-thread blocks, 256 q-rows each, 128-key barrier windows
    attn_mfma<<<dim3(8, 64), dim3(512), 0, stream>>>(QVR, VTg, Ob);

    // Wo projection
    mfma_gemm<false><<<dim3(128, 4), blk, 0, stream>>>(Ob, Wob, bob, AO, 512, 512, 512);

    // LN1
    ln1_kernel<<<MROWS, blk, 0, stream>>>(xb, AO, d_in[10], d_in[11], X1, flag);

    // FF1 (relu)
    mfma_gemm<true><<<dim3(128, 16), blk, 0, stream>>>(X1, Wf1t, bf1b, FFH, 512, 512, 2048);

    // FF2
    mfma_gemm<false><<<dim3(128, 4), blk, 0, stream>>>(FFH, Wf2t, bf2b, FF2, 2048, 2048, 512);

    // LN2 -> d_out
    ln2_kernel<<<MROWS, blk, 0, stream>>>(X1, FF2, d_in[16], d_in[17], d_out, flag);
}